// Round 1
// baseline (1448.672 us; speedup 1.0000x reference)
//
#include <hip/hip_runtime.h>
#include <math.h>

#define N_NODES 4096
#define BATCH 2

// ---------------------------------------------------------------------------
// Time block: out[b,n,t,o] = relu( c1 + sigmoid(c2) + c3 ),
//   ci = sum_{c,k} wi[o,c,k]*flow[b,n,t+k,c] + bi[o],  t in 0..2, o in 0..63
// x1 layout: [8192][192], col = t*64 + o
// ---------------------------------------------------------------------------
__global__ __launch_bounds__(192) void timeblock_kernel(
    const float* __restrict__ flow,
    const float* __restrict__ w1, const float* __restrict__ b1,
    const float* __restrict__ w2, const float* __restrict__ b2,
    const float* __restrict__ w3, const float* __restrict__ b3,
    float* __restrict__ x1)
{
    __shared__ float fl[8 * 5 * 192];      // 8 nodes of flow rows
    __shared__ float wl[3][64][25];        // 8 cc * 3 k = 24 (+1 pad)
    const int tid = threadIdx.x;
    const size_t base = (size_t)blockIdx.x * 8;   // node row base within 8192

    for (int i = tid; i < 8 * 5 * 192; i += 192)
        fl[i] = flow[base * 960 + i];

    const int t = tid / 64, o = tid & 63;
    float acc1[8], acc2[8], acc3[8];
#pragma unroll
    for (int nn = 0; nn < 8; ++nn) { acc1[nn] = 0.f; acc2[nn] = 0.f; acc3[nn] = 0.f; }

    for (int c0 = 0; c0 < 192; c0 += 8) {
        __syncthreads();
        for (int i = tid; i < 3 * 64 * 24; i += 192) {
            int conv = i / 1536, rem = i % 1536;
            int oo = rem / 24, q = rem % 24;
            int cc = q / 3, k = q % 3;
            const float* w = (conv == 0) ? w1 : (conv == 1 ? w2 : w3);
            wl[conv][oo][q] = w[(oo * 192 + c0 + cc) * 3 + k];
        }
        __syncthreads();
#pragma unroll
        for (int cc = 0; cc < 8; ++cc) {
#pragma unroll
            for (int k = 0; k < 3; ++k) {
                float wa = wl[0][o][cc * 3 + k];
                float wb = wl[1][o][cc * 3 + k];
                float wc = wl[2][o][cc * 3 + k];
#pragma unroll
                for (int nn = 0; nn < 8; ++nn) {
                    float f = fl[nn * 960 + (t + k) * 192 + c0 + cc];
                    acc1[nn] += wa * f;
                    acc2[nn] += wb * f;
                    acc3[nn] += wc * f;
                }
            }
        }
    }
    const float bb1 = b1[o], bb2 = b2[o], bb3 = b3[o];
    for (int nn = 0; nn < 8; ++nn) {
        float sg = 1.0f / (1.0f + __expf(-(acc2[nn] + bb2)));
        float v = (acc1[nn] + bb1) + sg + (acc3[nn] + bb3);
        x1[(base + nn) * 192 + t * 64 + o] = v > 0.f ? v : 0.f;
    }
}

// ---------------------------------------------------------------------------
// linear64: out[(b*H+g)*N + n][d] = sum_c in[b*N+n][c] * W[g*64+d][c]
// grid: (8192/64, H); 256 threads; 4x4 register micro-tile.
// ---------------------------------------------------------------------------
__global__ __launch_bounds__(256) void linear64_kernel(
    const float* __restrict__ in, const float* __restrict__ W,
    float* __restrict__ out, int C, int H)
{
    __shared__ float xs[64][68];
    __shared__ float wsm[64][68];
    const int tid = threadIdx.x;
    const int g = blockIdx.y;
    const int rowbase = blockIdx.x * 64;     // within 0..8191
    const int rgrp = tid >> 4, cgrp = tid & 15;

    float acc[4][4] = {};
    for (int c0 = 0; c0 < C; c0 += 64) {
        __syncthreads();
        for (int i = tid; i < 4096; i += 256) {
            int r = i >> 6, cc = i & 63;
            xs[r][cc]  = in[(size_t)(rowbase + r) * C + c0 + cc];
            wsm[r][cc] = W[(size_t)(g * 64 + r) * C + c0 + cc];
        }
        __syncthreads();
        for (int cc = 0; cc < 64; cc += 4) {
            float4 xv[4], wv[4];
#pragma unroll
            for (int i = 0; i < 4; ++i)
                xv[i] = *reinterpret_cast<const float4*>(&xs[4 * rgrp + i][cc]);
#pragma unroll
            for (int j = 0; j < 4; ++j)
                wv[j] = *reinterpret_cast<const float4*>(&wsm[4 * cgrp + j][cc]);
#pragma unroll
            for (int i = 0; i < 4; ++i) {
#pragma unroll
                for (int j = 0; j < 4; ++j) {
                    acc[i][j] += xv[i].x * wv[j].x + xv[i].y * wv[j].y
                               + xv[i].z * wv[j].z + xv[i].w * wv[j].w;
                }
            }
        }
    }
#pragma unroll
    for (int i = 0; i < 4; ++i) {
        int row = rowbase + 4 * rgrp + i;
        int b = row >> 12;         // /4096
        int n = row & 4095;
        float4 v = make_float4(acc[i][0], acc[i][1], acc[i][2], acc[i][3]);
        *reinterpret_cast<float4*>(
            &out[(((size_t)b * H + g) * N_NODES + n) * 64 + 4 * cgrp]) = v;
    }
}

// ---------------------------------------------------------------------------
// flash_gat: masked-softmax attention, fp32, online softmax.
//   s = (h_r . h_c) * graph; s==0 -> -1e16; softmax over cols; O = P @ h_c
//   out[row][d] = leaky_relu(O/l + bias)
// grid: (N/64, B*H); 256 threads; thread owns 4 rows x 4 cols.
// ---------------------------------------------------------------------------
__device__ inline float grp16_max(float v) {
    v = fmaxf(v, __shfl_xor(v, 1));
    v = fmaxf(v, __shfl_xor(v, 2));
    v = fmaxf(v, __shfl_xor(v, 4));
    v = fmaxf(v, __shfl_xor(v, 8));
    return v;
}
__device__ inline float grp16_sum(float v) {
    v += __shfl_xor(v, 1);
    v += __shfl_xor(v, 2);
    v += __shfl_xor(v, 4);
    v += __shfl_xor(v, 8);
    return v;
}

__global__ __launch_bounds__(256) void flash_gat_kernel(
    const float* __restrict__ hsrc, const float* __restrict__ graph,
    const float* __restrict__ bias, float* __restrict__ out,
    int H, int rstride)
{
    __shared__ float hr[64][68];
    __shared__ float hc[64][68];
    __shared__ float Pt[64][68];
    const int tid = threadIdx.x;
    const int by = blockIdx.y;
    const int b = by / H, head = by % H;
    const float* hs = hsrc + (size_t)by * N_NODES * 64;
    const int rowbase = blockIdx.x * 64;
    const int rgrp = tid >> 4, cgrp = tid & 15;

    for (int i = tid; i < 4096; i += 256) {
        int r = i >> 6, c = i & 63;
        hr[r][c] = hs[(size_t)(rowbase + r) * 64 + c];
    }

    float m[4], l[4], O[4][4];
#pragma unroll
    for (int i = 0; i < 4; ++i) {
        m[i] = -3.0e38f; l[i] = 0.f;
#pragma unroll
        for (int j = 0; j < 4; ++j) O[i][j] = 0.f;
    }

    for (int mt = 0; mt < N_NODES / 64; ++mt) {
        const int colbase = mt * 64;
        __syncthreads();   // prev tile's hc/Pt fully consumed
        for (int i = tid; i < 4096; i += 256) {
            int r = i >> 6, c = i & 63;
            hc[r][c] = hs[(size_t)(colbase + r) * 64 + c];
        }
        __syncthreads();

        // graph tile (L2/L3-resident; reused by all B*H attention maps)
        float4 g4[4];
#pragma unroll
        for (int i = 0; i < 4; ++i)
            g4[i] = *reinterpret_cast<const float4*>(
                &graph[(size_t)(rowbase + 4 * rgrp + i) * N_NODES + colbase + 4 * cgrp]);

        // ---- S = hr . hc^T (4x4 per thread, K=64) ----
        float s[4][4] = {};
        for (int k = 0; k < 64; k += 4) {
            float4 a0 = *reinterpret_cast<const float4*>(&hr[4 * rgrp + 0][k]);
            float4 a1 = *reinterpret_cast<const float4*>(&hr[4 * rgrp + 1][k]);
            float4 a2 = *reinterpret_cast<const float4*>(&hr[4 * rgrp + 2][k]);
            float4 a3 = *reinterpret_cast<const float4*>(&hr[4 * rgrp + 3][k]);
            float4 c0 = *reinterpret_cast<const float4*>(&hc[4 * cgrp + 0][k]);
            float4 c1 = *reinterpret_cast<const float4*>(&hc[4 * cgrp + 1][k]);
            float4 c2 = *reinterpret_cast<const float4*>(&hc[4 * cgrp + 2][k]);
            float4 c3 = *reinterpret_cast<const float4*>(&hc[4 * cgrp + 3][k]);
#define SFMA(i, A) \
            s[i][0] += A.x*c0.x + A.y*c0.y + A.z*c0.z + A.w*c0.w; \
            s[i][1] += A.x*c1.x + A.y*c1.y + A.z*c1.z + A.w*c1.w; \
            s[i][2] += A.x*c2.x + A.y*c2.y + A.z*c2.z + A.w*c2.w; \
            s[i][3] += A.x*c3.x + A.y*c3.y + A.z*c3.z + A.w*c3.w;
            SFMA(0, a0) SFMA(1, a1) SFMA(2, a2) SFMA(3, a3)
#undef SFMA
        }

        // ---- mask + online softmax ----
#pragma unroll
        for (int i = 0; i < 4; ++i) {
            float gm0 = (i == 0 ? g4[0].x : i == 1 ? g4[1].x : i == 2 ? g4[2].x : g4[3].x);
            float gm1 = (i == 0 ? g4[0].y : i == 1 ? g4[1].y : i == 2 ? g4[2].y : g4[3].y);
            float gm2 = (i == 0 ? g4[0].z : i == 1 ? g4[1].z : i == 2 ? g4[2].z : g4[3].z);
            float gm3 = (i == 0 ? g4[0].w : i == 1 ? g4[1].w : i == 2 ? g4[2].w : g4[3].w);
            float v0 = s[i][0] * gm0; s[i][0] = (v0 == 0.f) ? -1e16f : v0;
            float v1 = s[i][1] * gm1; s[i][1] = (v1 == 0.f) ? -1e16f : v1;
            float v2 = s[i][2] * gm2; s[i][2] = (v2 == 0.f) ? -1e16f : v2;
            float v3 = s[i][3] * gm3; s[i][3] = (v3 == 0.f) ? -1e16f : v3;

            float tm = fmaxf(fmaxf(s[i][0], s[i][1]), fmaxf(s[i][2], s[i][3]));
            tm = grp16_max(tm);
            float mn = fmaxf(m[i], tm);
            float corr = __expf(m[i] - mn);
            float p0 = __expf(s[i][0] - mn);
            float p1 = __expf(s[i][1] - mn);
            float p2 = __expf(s[i][2] - mn);
            float p3 = __expf(s[i][3] - mn);
            float rs = grp16_sum(p0 + p1 + p2 + p3);
            l[i] = l[i] * corr + rs;
            m[i] = mn;
            O[i][0] *= corr; O[i][1] *= corr; O[i][2] *= corr; O[i][3] *= corr;
            *reinterpret_cast<float4*>(&Pt[4 * rgrp + i][4 * cgrp]) =
                make_float4(p0, p1, p2, p3);
        }
        __syncthreads();

        // ---- O += P @ hc ----
        for (int mm = 0; mm < 64; mm += 4) {
            float4 p0 = *reinterpret_cast<const float4*>(&Pt[4 * rgrp + 0][mm]);
            float4 p1 = *reinterpret_cast<const float4*>(&Pt[4 * rgrp + 1][mm]);
            float4 p2 = *reinterpret_cast<const float4*>(&Pt[4 * rgrp + 2][mm]);
            float4 p3 = *reinterpret_cast<const float4*>(&Pt[4 * rgrp + 3][mm]);
            float4 h0 = *reinterpret_cast<const float4*>(&hc[mm + 0][4 * cgrp]);
            float4 h1v = *reinterpret_cast<const float4*>(&hc[mm + 1][4 * cgrp]);
            float4 h2v = *reinterpret_cast<const float4*>(&hc[mm + 2][4 * cgrp]);
            float4 h3 = *reinterpret_cast<const float4*>(&hc[mm + 3][4 * cgrp]);
#define PVFMA(i, P) \
            O[i][0] += P.x*h0.x + P.y*h1v.x + P.z*h2v.x + P.w*h3.x; \
            O[i][1] += P.x*h0.y + P.y*h1v.y + P.z*h2v.y + P.w*h3.y; \
            O[i][2] += P.x*h0.z + P.y*h1v.z + P.z*h2v.z + P.w*h3.z; \
            O[i][3] += P.x*h0.w + P.y*h1v.w + P.z*h2v.w + P.w*h3.w;
            PVFMA(0, p0) PVFMA(1, p1) PVFMA(2, p2) PVFMA(3, p3)
#undef PVFMA
        }
    }

    // ---- epilogue: normalize, bias, leaky_relu, store ----
    const float* bv = bias + head * 64;
    float4 bvv = *reinterpret_cast<const float4*>(&bv[4 * cgrp]);
    float* ob = out + ((size_t)b * N_NODES) * rstride + head * 64;
#pragma unroll
    for (int i = 0; i < 4; ++i) {
        int row = rowbase + 4 * rgrp + i;
        float inv = 1.0f / l[i];
        float v0 = O[i][0] * inv + bvv.x;
        float v1 = O[i][1] * inv + bvv.y;
        float v2 = O[i][2] * inv + bvv.z;
        float v3 = O[i][3] * inv + bvv.w;
        v0 = v0 > 0.f ? v0 : 0.01f * v0;
        v1 = v1 > 0.f ? v1 : 0.01f * v1;
        v2 = v2 > 0.f ? v2 : 0.01f * v2;
        v3 = v3 > 0.f ? v3 : 0.01f * v3;
        *reinterpret_cast<float4*>(&ob[(size_t)row * rstride + 4 * cgrp]) =
            make_float4(v0, v1, v2, v3);
    }
}

// ---------------------------------------------------------------------------
extern "C" void kernel_launch(void* const* d_in, const int* in_sizes, int n_in,
                              void* d_out, int out_size, void* d_ws, size_t ws_size,
                              hipStream_t stream)
{
    const float* flow = (const float*)d_in[0];
    const float* graph = (const float*)d_in[1];
    const float* w1 = (const float*)d_in[2];
    const float* b1 = (const float*)d_in[3];
    const float* w2 = (const float*)d_in[4];
    const float* b2 = (const float*)d_in[5];
    const float* w3 = (const float*)d_in[6];
    const float* b3 = (const float*)d_in[7];
    const float* Wh = (const float*)d_in[8];
    const float* bh = (const float*)d_in[9];
    const float* Wo = (const float*)d_in[10];
    const float* bo = (const float*)d_in[11];

    float* ws = (float*)d_ws;
    float* x1 = ws;                               // 8192*192
    float* h1 = x1 + (size_t)8192 * 192;          // 8*4096*64
    float* x2 = h1 + (size_t)8 * 4096 * 64;       // 8192*256
    float* h2 = x2 + (size_t)8192 * 256;          // 8192*64
    float* outp = (float*)d_out;

    hipLaunchKernelGGL(timeblock_kernel, dim3(1024), dim3(192), 0, stream,
                       flow, w1, b1, w2, b2, w3, b3, x1);
    hipLaunchKernelGGL(linear64_kernel, dim3(128, 4), dim3(256), 0, stream,
                       x1, Wh, h1, 192, 4);
    hipLaunchKernelGGL(flash_gat_kernel, dim3(64, 8), dim3(256), 0, stream,
                       h1, graph, bh, x2, 4, 256);
    hipLaunchKernelGGL(linear64_kernel, dim3(128, 1), dim3(256), 0, stream,
                       x2, Wo, h2, 256, 1);
    hipLaunchKernelGGL(flash_gat_kernel, dim3(64, 2), dim3(256), 0, stream,
                       h2, graph, bo, outp, 1, 64);
}

// Round 3
// 1063.598 us; speedup vs baseline: 1.3620x; 1.3620x over previous
//
#include <hip/hip_runtime.h>
#include <math.h>

#define N_NODES 4096

typedef unsigned short u16;
typedef unsigned int u32;

typedef __attribute__((ext_vector_type(8))) short bfrag;   // 8 bf16 = 4 VGPR
typedef __attribute__((ext_vector_type(4))) float f4;

__device__ __forceinline__ u16 f2bf(float x) {
    union { float f; u32 u; } v; v.f = x;
    u32 r = (v.u + 0x7FFFu + ((v.u >> 16) & 1u)) >> 16;   // RNE
    return (u16)r;
}
__device__ __forceinline__ float bf2f(u16 b) {
    union { float f; u32 u; } v; v.u = ((u32)b) << 16; return v.f;
}

// ---------------------------------------------------------------------------
// Time block: x1[8192][192], col = t*64 + o
// ---------------------------------------------------------------------------
__global__ __launch_bounds__(192) void timeblock_kernel(
    const float* __restrict__ flow,
    const float* __restrict__ w1, const float* __restrict__ b1,
    const float* __restrict__ w2, const float* __restrict__ b2,
    const float* __restrict__ w3, const float* __restrict__ b3,
    float* __restrict__ x1)
{
    __shared__ float fl[8 * 5 * 192];
    __shared__ float wl[3][64][25];
    const int tid = threadIdx.x;
    const size_t base = (size_t)blockIdx.x * 8;

    for (int i = tid; i < 8 * 5 * 192; i += 192)
        fl[i] = flow[base * 960 + i];

    const int t = tid / 64, o = tid & 63;
    float acc1[8], acc2[8], acc3[8];
#pragma unroll
    for (int nn = 0; nn < 8; ++nn) { acc1[nn] = 0.f; acc2[nn] = 0.f; acc3[nn] = 0.f; }

    for (int c0 = 0; c0 < 192; c0 += 8) {
        __syncthreads();
        for (int i = tid; i < 3 * 64 * 24; i += 192) {
            int conv = i / 1536, rem = i % 1536;
            int oo = rem / 24, q = rem % 24;
            int cc = q / 3, k = q % 3;
            const float* w = (conv == 0) ? w1 : (conv == 1 ? w2 : w3);
            wl[conv][oo][q] = w[(oo * 192 + c0 + cc) * 3 + k];
        }
        __syncthreads();
#pragma unroll
        for (int cc = 0; cc < 8; ++cc) {
#pragma unroll
            for (int k = 0; k < 3; ++k) {
                float wa = wl[0][o][cc * 3 + k];
                float wb = wl[1][o][cc * 3 + k];
                float wc = wl[2][o][cc * 3 + k];
#pragma unroll
                for (int nn = 0; nn < 8; ++nn) {
                    float f = fl[nn * 960 + (t + k) * 192 + c0 + cc];
                    acc1[nn] += wa * f;
                    acc2[nn] += wb * f;
                    acc3[nn] += wc * f;
                }
            }
        }
    }
    const float bb1 = b1[o], bb2 = b2[o], bb3 = b3[o];
    for (int nn = 0; nn < 8; ++nn) {
        float sg = 1.0f / (1.0f + __expf(-(acc2[nn] + bb2)));
        float v = (acc1[nn] + bb1) + sg + (acc3[nn] + bb3);
        x1[(base + nn) * 192 + t * 64 + o] = v > 0.f ? v : 0.f;
    }
}

// ---------------------------------------------------------------------------
// linear64_split: h = in @ W^T per head, emitted as bf16 hi/lo in node-major
// ([map][n][64]) and feat-major ([map][64][4096]) layouts.
// ---------------------------------------------------------------------------
__global__ __launch_bounds__(256) void linear64_split_kernel(
    const float* __restrict__ in, const float* __restrict__ W,
    u16* __restrict__ h_hi, u16* __restrict__ h_lo,
    u16* __restrict__ hT_hi, u16* __restrict__ hT_lo,
    int C, int H)
{
    __shared__ float xs[64][68];
    __shared__ float wsm[64][68];
    const int tid = threadIdx.x;
    const int g = blockIdx.y;
    const int rowbase = blockIdx.x * 64;
    const int rgrp = tid >> 4, cgrp = tid & 15;

    float acc[4][4] = {};
    for (int c0 = 0; c0 < C; c0 += 64) {
        __syncthreads();
        for (int i = tid; i < 4096; i += 256) {
            int r = i >> 6, cc = i & 63;
            xs[r][cc]  = in[(size_t)(rowbase + r) * C + c0 + cc];
            wsm[r][cc] = W[(size_t)(g * 64 + r) * C + c0 + cc];
        }
        __syncthreads();
        for (int cc = 0; cc < 64; cc += 4) {
            float4 xv[4], wv[4];
#pragma unroll
            for (int i = 0; i < 4; ++i)
                xv[i] = *reinterpret_cast<const float4*>(&xs[4 * rgrp + i][cc]);
#pragma unroll
            for (int j = 0; j < 4; ++j)
                wv[j] = *reinterpret_cast<const float4*>(&wsm[4 * cgrp + j][cc]);
#pragma unroll
            for (int i = 0; i < 4; ++i) {
#pragma unroll
                for (int j = 0; j < 4; ++j) {
                    acc[i][j] += xv[i].x * wv[j].x + xv[i].y * wv[j].y
                               + xv[i].z * wv[j].z + xv[i].w * wv[j].w;
                }
            }
        }
    }

    u16 hi[4][4], lo[4][4];
#pragma unroll
    for (int i = 0; i < 4; ++i)
#pragma unroll
        for (int j = 0; j < 4; ++j) {
            float a = acc[i][j];
            u16 h = f2bf(a);
            hi[i][j] = h;
            lo[i][j] = f2bf(a - bf2f(h));
        }

    const int b = rowbase >> 12;
    const size_t mapb = (size_t)(b * H + g) * (4096 * 64);

#pragma unroll
    for (int i = 0; i < 4; ++i) {
        int n = (rowbase & 4095) + 4 * rgrp + i;
        ushort4 vh = { hi[i][0], hi[i][1], hi[i][2], hi[i][3] };
        ushort4 vl = { lo[i][0], lo[i][1], lo[i][2], lo[i][3] };
        *(ushort4*)&h_hi[mapb + (size_t)n * 64 + 4 * cgrp] = vh;
        *(ushort4*)&h_lo[mapb + (size_t)n * 64 + 4 * cgrp] = vl;
    }
#pragma unroll
    for (int j = 0; j < 4; ++j) {
        int d = 4 * cgrp + j;
        int n0 = (rowbase & 4095) + 4 * rgrp;
        ushort4 vh = { hi[0][j], hi[1][j], hi[2][j], hi[3][j] };
        ushort4 vl = { lo[0][j], lo[1][j], lo[2][j], lo[3][j] };
        *(ushort4*)&hT_hi[mapb + (size_t)d * 4096 + n0] = vh;
        *(ushort4*)&hT_lo[mapb + (size_t)d * 4096 + n0] = vl;
    }
}

// ---------------------------------------------------------------------------
// flash_mfma: masked-softmax attention via bf16-split MFMA.
//   S = hr_hi.hc_hi + hr_hi.hc_lo + hr_lo.hc_hi  (fp32 acc)
//   mask: v = s*graph; v==0 -> -1e16; online softmax (fp32)
//   O += P_hi@V_hi + P_hi@V_lo + P_lo@V_hi   (P split hi/lo — kills the
//   correlated per-row scale error that cascaded into GAT-2 logit flips)
// ---------------------------------------------------------------------------
__device__ __forceinline__ float grp16_max(float v) {
    v = fmaxf(v, __shfl_xor(v, 1));
    v = fmaxf(v, __shfl_xor(v, 2));
    v = fmaxf(v, __shfl_xor(v, 4));
    v = fmaxf(v, __shfl_xor(v, 8));
    return v;
}
__device__ __forceinline__ float grp16_sum(float v) {
    v += __shfl_xor(v, 1);
    v += __shfl_xor(v, 2);
    v += __shfl_xor(v, 4);
    v += __shfl_xor(v, 8);
    return v;
}

__global__ __launch_bounds__(256) void flash_mfma_kernel(
    const u16* __restrict__ h_hi, const u16* __restrict__ h_lo,
    const u16* __restrict__ hT_hi, const u16* __restrict__ hT_lo,
    const float* __restrict__ graph, const float* __restrict__ bias,
    float* __restrict__ out, int H, int rstride)
{
    __shared__ __align__(16) u16 hcs[2][4][4096];   // [dbuf][hc_hi,hc_lo,hcT_hi,hcT_lo]
    __shared__ __align__(16) u16 Ps[2][4096];       // [P_hi, P_lo]

    const int tid = threadIdx.x;
    const int wv = tid >> 6;
    const int l = tid & 63;
    const int ln15 = l & 15, ln16 = l >> 4;
    const int by = blockIdx.y;
    const int bb = by / H, head = by % H;
    const size_t mapb = (size_t)by * (4096 * 64);
    const int rowbase = blockIdx.x * 64;

    const int arow = rowbase + wv * 16 + ln15;
    bfrag ahi[2], alo[2];
#pragma unroll
    for (int ks = 0; ks < 2; ++ks) {
        ahi[ks] = *(const bfrag*)(h_hi + mapb + (size_t)arow * 64 + ks * 32 + ln16 * 8);
        alo[ks] = *(const bfrag*)(h_lo + mapb + (size_t)arow * 64 + ks * 32 + ln16 * 8);
    }

    const u16* gA = (wv == 0 ? h_hi : wv == 1 ? h_lo : wv == 2 ? hT_hi : hT_lo) + mapb;
    const int srow = l;
    const int swz = (srow & 7) << 3;

    uint4 L[8];
    {
        size_t be = (wv < 2) ? (size_t)srow * 64 : (size_t)srow * 4096;
#pragma unroll
        for (int j = 0; j < 8; ++j)
            L[j] = *(const uint4*)(gA + be + j * 8);
    }

    const float* grow = graph + (size_t)(rowbase + wv * 16 + ln16 * 4) * 4096 + ln15;

    float m_[4], l_[4];
    f4 acco[4];
#pragma unroll
    for (int i = 0; i < 4; ++i) {
        m_[i] = -3.0e38f; l_[i] = 0.f;
        acco[i][0] = 0.f; acco[i][1] = 0.f; acco[i][2] = 0.f; acco[i][3] = 0.f;
    }

    for (int t = 0; t < 64; ++t) {
        const int cur = t & 1;

#pragma unroll
        for (int j = 0; j < 8; ++j)
            *(uint4*)&hcs[cur][wv][srow * 64 + ((j * 8) ^ swz)] = L[j];

        if (t + 1 < 64) {
            size_t be = (wv < 2) ? (size_t)((t + 1) * 64 + srow) * 64
                                 : (size_t)srow * 4096 + (t + 1) * 64;
#pragma unroll
            for (int j = 0; j < 8; ++j)
                L[j] = *(const uint4*)(gA + be + j * 8);
        }

        const float* gp = grow + (size_t)t * 64;
        float gr[4][4];
#pragma unroll
        for (int rg = 0; rg < 4; ++rg)
#pragma unroll
            for (int cb = 0; cb < 4; ++cb)
                gr[rg][cb] = gp[(size_t)rg * 4096 + cb * 16];

        __syncthreads();

        // ---- S phase: 24 MFMAs ----
        f4 accs[4];
#pragma unroll
        for (int cb = 0; cb < 4; ++cb) {
            f4 a; a[0] = 0.f; a[1] = 0.f; a[2] = 0.f; a[3] = 0.f;
#pragma unroll
            for (int ks = 0; ks < 2; ++ks) {
                int c = cb * 16 + ln15;
                int idx = c * 64 + (((ks * 4 + ln16) * 8) ^ ((c & 7) << 3));
                bfrag bhi = *(const bfrag*)&hcs[cur][0][idx];
                bfrag blo = *(const bfrag*)&hcs[cur][1][idx];
                a = __builtin_amdgcn_mfma_f32_16x16x32_bf16(ahi[ks], bhi, a, 0, 0, 0);
                a = __builtin_amdgcn_mfma_f32_16x16x32_bf16(alo[ks], bhi, a, 0, 0, 0);
                a = __builtin_amdgcn_mfma_f32_16x16x32_bf16(ahi[ks], blo, a, 0, 0, 0);
            }
            accs[cb] = a;
        }

        // ---- mask + online softmax; write P hi/lo (bf16) ----
#pragma unroll
        for (int rg = 0; rg < 4; ++rg) {
            float vs[4];
#pragma unroll
            for (int cb = 0; cb < 4; ++cb) {
                float v = accs[cb][rg] * gr[rg][cb];
                vs[cb] = (v == 0.f) ? -1e16f : v;
            }
            float tm = fmaxf(fmaxf(vs[0], vs[1]), fmaxf(vs[2], vs[3]));
            tm = grp16_max(tm);
            float mn = fmaxf(m_[rg], tm);
            float corr = __expf(m_[rg] - mn);
            float p[4];
            p[0] = __expf(vs[0] - mn);
            p[1] = __expf(vs[1] - mn);
            p[2] = __expf(vs[2] - mn);
            p[3] = __expf(vs[3] - mn);
            float rs = grp16_sum(p[0] + p[1] + p[2] + p[3]);
            l_[rg] = l_[rg] * corr + rs;
            m_[rg] = mn;
#pragma unroll
            for (int nb = 0; nb < 4; ++nb) acco[nb][rg] *= corr;

            int prow = wv * 16 + ln16 * 4 + rg;
            int psw = (prow & 7) << 3;
#pragma unroll
            for (int cb = 0; cb < 4; ++cb) {
                int idx = prow * 64 + ((cb * 16 + ln15) ^ psw);
                u16 ph = f2bf(p[cb]);
                Ps[0][idx] = ph;
                Ps[1][idx] = f2bf(p[cb] - bf2f(ph));
            }
        }

        __syncthreads();

        // ---- PV phase: 24 MFMAs ----
        bfrag pfh[2], pfl[2];
#pragma unroll
        for (int ks = 0; ks < 2; ++ks) {
            int pr = wv * 16 + ln15;
            int idx = pr * 64 + (((ks * 4 + ln16) * 8) ^ ((pr & 7) << 3));
            pfh[ks] = *(const bfrag*)&Ps[0][idx];
            pfl[ks] = *(const bfrag*)&Ps[1][idx];
        }
#pragma unroll
        for (int nb = 0; nb < 4; ++nb) {
#pragma unroll
            for (int ks = 0; ks < 2; ++ks) {
                int nr = nb * 16 + ln15;
                int idx = nr * 64 + (((ks * 4 + ln16) * 8) ^ ((nr & 7) << 3));
                bfrag vhi = *(const bfrag*)&hcs[cur][2][idx];
                bfrag vlo = *(const bfrag*)&hcs[cur][3][idx];
                acco[nb] = __builtin_amdgcn_mfma_f32_16x16x32_bf16(pfh[ks], vhi, acco[nb], 0, 0, 0);
                acco[nb] = __builtin_amdgcn_mfma_f32_16x16x32_bf16(pfh[ks], vlo, acco[nb], 0, 0, 0);
                acco[nb] = __builtin_amdgcn_mfma_f32_16x16x32_bf16(pfl[ks], vhi, acco[nb], 0, 0, 0);
            }
        }
    }

    // ---- epilogue ----
    const float* bv = bias + head * 64;
#pragma unroll
    for (int rg = 0; rg < 4; ++rg) {
        int row = rowbase + wv * 16 + ln16 * 4 + rg;
        float inv = 1.0f / l_[rg];
#pragma unroll
        for (int nb = 0; nb < 4; ++nb) {
            float v = acco[nb][rg] * inv + bv[nb * 16 + ln15];
            v = v > 0.f ? v : 0.01f * v;
            out[(size_t)(bb * N_NODES + row) * rstride + head * 64 + nb * 16 + ln15] = v;
        }
    }
}

// ---------------------------------------------------------------------------
extern "C" void kernel_launch(void* const* d_in, const int* in_sizes, int n_in,
                              void* d_out, int out_size, void* d_ws, size_t ws_size,
                              hipStream_t stream)
{
    const float* flow = (const float*)d_in[0];
    const float* graph = (const float*)d_in[1];
    const float* w1 = (const float*)d_in[2];
    const float* b1 = (const float*)d_in[3];
    const float* w2 = (const float*)d_in[4];
    const float* b2 = (const float*)d_in[5];
    const float* w3 = (const float*)d_in[6];
    const float* b3 = (const float*)d_in[7];
    const float* Wh = (const float*)d_in[8];
    const float* bh = (const float*)d_in[9];
    const float* Wo = (const float*)d_in[10];
    const float* bo = (const float*)d_in[11];

    char* ws = (char*)d_ws;
    u16* h1_hi  = (u16*)ws;
    u16* h1_lo  = h1_hi + (size_t)8 * 4096 * 64;
    u16* h1T_hi = h1_lo + (size_t)8 * 4096 * 64;
    u16* h1T_lo = h1T_hi + (size_t)8 * 4096 * 64;
    u16* h2_hi  = (u16*)ws;                          // reuse h1 region
    u16* h2_lo  = h2_hi + (size_t)2 * 4096 * 64;
    u16* h2T_hi = h2_lo + (size_t)2 * 4096 * 64;
    u16* h2T_lo = h2T_hi + (size_t)2 * 4096 * 64;
    float* xreg = (float*)(ws + (size_t)4 * 8 * 4096 * 64 * 2);  // x1 / x2 aliased
    float* x1 = xreg;
    float* x2 = xreg;
    float* outp = (float*)d_out;

    hipLaunchKernelGGL(timeblock_kernel, dim3(1024), dim3(192), 0, stream,
                       flow, w1, b1, w2, b2, w3, b3, x1);
    hipLaunchKernelGGL(linear64_split_kernel, dim3(128, 4), dim3(256), 0, stream,
                       x1, Wh, h1_hi, h1_lo, h1T_hi, h1T_lo, 192, 4);
    hipLaunchKernelGGL(flash_mfma_kernel, dim3(64, 8), dim3(256), 0, stream,
                       h1_hi, h1_lo, h1T_hi, h1T_lo, graph, bh, x2, 4, 256);
    hipLaunchKernelGGL(linear64_split_kernel, dim3(128, 1), dim3(256), 0, stream,
                       x2, Wo, h2_hi, h2_lo, h2T_hi, h2T_lo, 256, 1);
    hipLaunchKernelGGL(flash_mfma_kernel, dim3(64, 2), dim3(256), 0, stream,
                       h2_hi, h2_lo, h2T_hi, h2T_lo, graph, bo, outp, 1, 64);
}

// Round 4
// 652.176 us; speedup vs baseline: 2.2213x; 1.6308x over previous
//
#include <hip/hip_runtime.h>
#include <math.h>

#define N_NODES 4096

typedef unsigned short u16;
typedef unsigned int u32;

typedef __attribute__((ext_vector_type(8))) short bfrag;   // 8 bf16 = 4 VGPR
typedef __attribute__((ext_vector_type(4))) float f4;

__device__ __forceinline__ u16 f2bf(float x) {
    union { float f; u32 u; } v; v.f = x;
    u32 r = (v.u + 0x7FFFu + ((v.u >> 16) & 1u)) >> 16;   // RNE
    return (u16)r;
}
__device__ __forceinline__ float bf2f(u16 b) {
    union { float f; u32 u; } v; v.u = ((u32)b) << 16; return v.f;
}

// ---------------------------------------------------------------------------
// Time block: x1[8192][192], col = t*64 + o
// ---------------------------------------------------------------------------
__global__ __launch_bounds__(192) void timeblock_kernel(
    const float* __restrict__ flow,
    const float* __restrict__ w1, const float* __restrict__ b1,
    const float* __restrict__ w2, const float* __restrict__ b2,
    const float* __restrict__ w3, const float* __restrict__ b3,
    float* __restrict__ x1)
{
    __shared__ float fl[8 * 5 * 192];
    __shared__ float wl[3][64][25];
    const int tid = threadIdx.x;
    const size_t base = (size_t)blockIdx.x * 8;

    for (int i = tid; i < 8 * 5 * 192; i += 192)
        fl[i] = flow[base * 960 + i];

    const int t = tid / 64, o = tid & 63;
    float acc1[8], acc2[8], acc3[8];
#pragma unroll
    for (int nn = 0; nn < 8; ++nn) { acc1[nn] = 0.f; acc2[nn] = 0.f; acc3[nn] = 0.f; }

    for (int c0 = 0; c0 < 192; c0 += 8) {
        __syncthreads();
        for (int i = tid; i < 3 * 64 * 24; i += 192) {
            int conv = i / 1536, rem = i % 1536;
            int oo = rem / 24, q = rem % 24;
            int cc = q / 3, k = q % 3;
            const float* w = (conv == 0) ? w1 : (conv == 1 ? w2 : w3);
            wl[conv][oo][q] = w[(oo * 192 + c0 + cc) * 3 + k];
        }
        __syncthreads();
#pragma unroll
        for (int cc = 0; cc < 8; ++cc) {
#pragma unroll
            for (int k = 0; k < 3; ++k) {
                float wa = wl[0][o][cc * 3 + k];
                float wb = wl[1][o][cc * 3 + k];
                float wc = wl[2][o][cc * 3 + k];
#pragma unroll
                for (int nn = 0; nn < 8; ++nn) {
                    float f = fl[nn * 960 + (t + k) * 192 + c0 + cc];
                    acc1[nn] += wa * f;
                    acc2[nn] += wb * f;
                    acc3[nn] += wc * f;
                }
            }
        }
    }
    const float bb1 = b1[o], bb2 = b2[o], bb3 = b3[o];
    for (int nn = 0; nn < 8; ++nn) {
        float sg = 1.0f / (1.0f + __expf(-(acc2[nn] + bb2)));
        float v = (acc1[nn] + bb1) + sg + (acc3[nn] + bb3);
        x1[(base + nn) * 192 + t * 64 + o] = v > 0.f ? v : 0.f;
    }
}

// ---------------------------------------------------------------------------
// linear64_split: h = in @ W^T per head, emitted as bf16 hi/lo in node-major
// ([map][n][64]) and TILE-BLOCKED feat-major ([map][tile][d][64]) layouts.
// The blocked layout makes each 64-col V tile 8KB-contiguous -> coalesced
// global_load_lds staging in flash (was a 64-line/instr gather before).
// ---------------------------------------------------------------------------
__global__ __launch_bounds__(256) void linear64_split_kernel(
    const float* __restrict__ in, const float* __restrict__ W,
    u16* __restrict__ h_hi, u16* __restrict__ h_lo,
    u16* __restrict__ hTb_hi, u16* __restrict__ hTb_lo,
    int C, int H)
{
    __shared__ float xs[64][68];
    __shared__ float wsm[64][68];
    const int tid = threadIdx.x;
    const int g = blockIdx.y;
    const int rowbase = blockIdx.x * 64;
    const int rgrp = tid >> 4, cgrp = tid & 15;

    float acc[4][4] = {};
    for (int c0 = 0; c0 < C; c0 += 64) {
        __syncthreads();
        for (int i = tid; i < 4096; i += 256) {
            int r = i >> 6, cc = i & 63;
            xs[r][cc]  = in[(size_t)(rowbase + r) * C + c0 + cc];
            wsm[r][cc] = W[(size_t)(g * 64 + r) * C + c0 + cc];
        }
        __syncthreads();
        for (int cc = 0; cc < 64; cc += 4) {
            float4 xv[4], wv[4];
#pragma unroll
            for (int i = 0; i < 4; ++i)
                xv[i] = *reinterpret_cast<const float4*>(&xs[4 * rgrp + i][cc]);
#pragma unroll
            for (int j = 0; j < 4; ++j)
                wv[j] = *reinterpret_cast<const float4*>(&wsm[4 * cgrp + j][cc]);
#pragma unroll
            for (int i = 0; i < 4; ++i) {
#pragma unroll
                for (int j = 0; j < 4; ++j) {
                    acc[i][j] += xv[i].x * wv[j].x + xv[i].y * wv[j].y
                               + xv[i].z * wv[j].z + xv[i].w * wv[j].w;
                }
            }
        }
    }

    u16 hi[4][4], lo[4][4];
#pragma unroll
    for (int i = 0; i < 4; ++i)
#pragma unroll
        for (int j = 0; j < 4; ++j) {
            float a = acc[i][j];
            u16 h = f2bf(a);
            hi[i][j] = h;
            lo[i][j] = f2bf(a - bf2f(h));
        }

    const int b = rowbase >> 12;
    const size_t mapb = (size_t)(b * H + g) * (4096 * 64);

    // node-major [map][n][64]
#pragma unroll
    for (int i = 0; i < 4; ++i) {
        int n = (rowbase & 4095) + 4 * rgrp + i;
        ushort4 vh = { hi[i][0], hi[i][1], hi[i][2], hi[i][3] };
        ushort4 vl = { lo[i][0], lo[i][1], lo[i][2], lo[i][3] };
        *(ushort4*)&h_hi[mapb + (size_t)n * 64 + 4 * cgrp] = vh;
        *(ushort4*)&h_lo[mapb + (size_t)n * 64 + 4 * cgrp] = vl;
    }
    // blocked feat-major [map][tile][d][64]; n0..n0+3 share one tile
    {
        int n0 = (rowbase & 4095) + 4 * rgrp;
        size_t tb = mapb + ((size_t)(n0 >> 6) * 64) * 64;
#pragma unroll
        for (int j = 0; j < 4; ++j) {
            int d = 4 * cgrp + j;
            ushort4 vh = { hi[0][j], hi[1][j], hi[2][j], hi[3][j] };
            ushort4 vl = { lo[0][j], lo[1][j], lo[2][j], lo[3][j] };
            *(ushort4*)&hTb_hi[tb + (size_t)d * 64 + (n0 & 63)] = vh;
            *(ushort4*)&hTb_lo[tb + (size_t)d * 64 + (n0 & 63)] = vl;
        }
    }
}

// ---------------------------------------------------------------------------
// flash_mfma: masked-softmax attention via bf16-split MFMA.
//   S = hr_hi.hc_hi + hr_hi.hc_lo + hr_lo.hc_hi  (fp32 acc)
//   mask: v = s*graph; v==0 -> -1e16; online softmax (fp32)
//   O += P_hi@V_hi + P_hi@V_lo + P_lo@V_hi
// Round-3 restructure: global_load_lds staging (pre-swizzled source, linear
// LDS dest), ONE barrier per tile (P is wave-local; hcs double-buffered),
// graph mask prefetched one tile ahead in registers.
// ---------------------------------------------------------------------------
__device__ __forceinline__ float grp16_max(float v) {
    v = fmaxf(v, __shfl_xor(v, 1));
    v = fmaxf(v, __shfl_xor(v, 2));
    v = fmaxf(v, __shfl_xor(v, 4));
    v = fmaxf(v, __shfl_xor(v, 8));
    return v;
}
__device__ __forceinline__ float grp16_sum(float v) {
    v += __shfl_xor(v, 1);
    v += __shfl_xor(v, 2);
    v += __shfl_xor(v, 4);
    v += __shfl_xor(v, 8);
    return v;
}

__global__ __launch_bounds__(256) void flash_mfma_kernel(
    const u16* __restrict__ h_hi, const u16* __restrict__ h_lo,
    const u16* __restrict__ hTb_hi, const u16* __restrict__ hTb_lo,
    const float* __restrict__ graph, const float* __restrict__ bias,
    float* __restrict__ out, int H, int rstride)
{
    __shared__ __align__(16) u16 hcs[2][4][4096];   // [dbuf][hc_hi,hc_lo,V_hi,V_lo]
    __shared__ __align__(16) u16 Ps[2][4096];       // [P_hi, P_lo] (wave-local rows)

    const int tid = threadIdx.x;
    const int wv = tid >> 6;
    const int l = tid & 63;
    const int ln15 = l & 15, ln16 = l >> 4;
    const int by = blockIdx.y;
    const int bb = by / H, head = by % H;
    const size_t mapb = (size_t)by * (4096 * 64);
    const int rowbase = blockIdx.x * 64;

    // ---- hr A-fragments (registers, whole block lifetime) ----
    const int arow = rowbase + wv * 16 + ln15;
    bfrag ahi[2], alo[2];
#pragma unroll
    for (int ks = 0; ks < 2; ++ks) {
        ahi[ks] = *(const bfrag*)(h_hi + mapb + (size_t)arow * 64 + ks * 32 + ln16 * 8);
        alo[ks] = *(const bfrag*)(h_lo + mapb + (size_t)arow * 64 + ks * 32 + ln16 * 8);
    }

    // ---- staging: wave wv owns array wv; pre-swizzled global source ----
    // LDS[r][jpos] = global[r][jpos ^ (r&7)]  (16B chunks), dest linear.
    const u16* gA = (wv == 0 ? h_hi : wv == 1 ? h_lo : wv == 2 ? hTb_hi : hTb_lo) + mapb;
    const int lrow = l >> 3;                         // row within 8-row group
    const int stoff = lrow * 64 + (((l & 7) ^ lrow) << 3);   // u16 elements

#define STAGE(T, BUF)                                                          \
    {                                                                          \
        const u16* srcp = gA + (size_t)(T) * 4096 + stoff;                     \
        u16* dstp = &hcs[BUF][wv][0];                                          \
        _Pragma("unroll")                                                      \
        for (int i_ = 0; i_ < 8; ++i_)                                         \
            __builtin_amdgcn_global_load_lds(                                  \
                (const __attribute__((address_space(1))) u32*)(srcp + i_ * 512), \
                (__attribute__((address_space(3))) u32*)(dstp + i_ * 512),     \
                16, 0, 0);                                                     \
    }

    const float* grow = graph + (size_t)(rowbase + wv * 16 + ln16 * 4) * 4096 + ln15;

    float m_[4], l_[4];
    f4 acco[4];
#pragma unroll
    for (int i = 0; i < 4; ++i) {
        m_[i] = -3.0e38f; l_[i] = 0.f;
        acco[i][0] = 0.f; acco[i][1] = 0.f; acco[i][2] = 0.f; acco[i][3] = 0.f;
    }

    // prologue: stage tile 0, load graph tile 0
    STAGE(0, 0);
    float grC[4][4], grN[4][4];
#pragma unroll
    for (int rg = 0; rg < 4; ++rg)
#pragma unroll
        for (int cb = 0; cb < 4; ++cb)
            grC[rg][cb] = grow[(size_t)rg * 4096 + cb * 16];

    for (int t = 0; t < 64; ++t) {
        const int cur = t & 1;

        __syncthreads();   // compiler drains vmcnt/lgkm: buf[cur] ready for all

        if (t < 63) {
            STAGE(t + 1, cur ^ 1);     // buf[cur^1] free (all waves past tile t-1)
#pragma unroll
            for (int rg = 0; rg < 4; ++rg)
#pragma unroll
                for (int cb = 0; cb < 4; ++cb)
                    grN[rg][cb] = grow[(size_t)rg * 4096 + (t + 1) * 64 + cb * 16];
        }

        // ---- S phase: 24 MFMAs ----
        f4 accs[4];
#pragma unroll
        for (int cb = 0; cb < 4; ++cb) {
            f4 a; a[0] = 0.f; a[1] = 0.f; a[2] = 0.f; a[3] = 0.f;
#pragma unroll
            for (int ks = 0; ks < 2; ++ks) {
                int c = cb * 16 + ln15;
                int idx = c * 64 + (((ks * 4 + ln16) * 8) ^ ((c & 7) << 3));
                bfrag bhi = *(const bfrag*)&hcs[cur][0][idx];
                bfrag blo = *(const bfrag*)&hcs[cur][1][idx];
                a = __builtin_amdgcn_mfma_f32_16x16x32_bf16(ahi[ks], bhi, a, 0, 0, 0);
                a = __builtin_amdgcn_mfma_f32_16x16x32_bf16(alo[ks], bhi, a, 0, 0, 0);
                a = __builtin_amdgcn_mfma_f32_16x16x32_bf16(ahi[ks], blo, a, 0, 0, 0);
            }
            accs[cb] = a;
        }

        // ---- mask + online softmax; write P hi/lo (wave-local LDS rows) ----
#pragma unroll
        for (int rg = 0; rg < 4; ++rg) {
            float vs[4];
#pragma unroll
            for (int cb = 0; cb < 4; ++cb) {
                float v = accs[cb][rg] * grC[rg][cb];
                vs[cb] = (v == 0.f) ? -1e16f : v;
            }
            float tm = fmaxf(fmaxf(vs[0], vs[1]), fmaxf(vs[2], vs[3]));
            tm = grp16_max(tm);
            float mn = fmaxf(m_[rg], tm);
            float corr = __expf(m_[rg] - mn);
            float p[4];
            p[0] = __expf(vs[0] - mn);
            p[1] = __expf(vs[1] - mn);
            p[2] = __expf(vs[2] - mn);
            p[3] = __expf(vs[3] - mn);
            float rs = grp16_sum(p[0] + p[1] + p[2] + p[3]);
            l_[rg] = l_[rg] * corr + rs;
            m_[rg] = mn;
#pragma unroll
            for (int nb = 0; nb < 4; ++nb) acco[nb][rg] *= corr;

            int prow = wv * 16 + ln16 * 4 + rg;
            int psw = (prow & 7) << 3;
#pragma unroll
            for (int cb = 0; cb < 4; ++cb) {
                int idx = prow * 64 + ((cb * 16 + ln15) ^ psw);
                u16 ph = f2bf(p[cb]);
                Ps[0][idx] = ph;
                Ps[1][idx] = f2bf(p[cb] - bf2f(ph));
            }
        }

        // ---- PV phase: 24 MFMAs (P rows are wave-local; lgkmcnt orders) ----
        bfrag pfh[2], pfl[2];
#pragma unroll
        for (int ks = 0; ks < 2; ++ks) {
            int pr = wv * 16 + ln15;
            int idx = pr * 64 + (((ks * 4 + ln16) * 8) ^ ((pr & 7) << 3));
            pfh[ks] = *(const bfrag*)&Ps[0][idx];
            pfl[ks] = *(const bfrag*)&Ps[1][idx];
        }
#pragma unroll
        for (int nb = 0; nb < 4; ++nb) {
#pragma unroll
            for (int ks = 0; ks < 2; ++ks) {
                int nr = nb * 16 + ln15;
                int idx = nr * 64 + (((ks * 4 + ln16) * 8) ^ ((nr & 7) << 3));
                bfrag vhi = *(const bfrag*)&hcs[cur][2][idx];
                bfrag vlo = *(const bfrag*)&hcs[cur][3][idx];
                acco[nb] = __builtin_amdgcn_mfma_f32_16x16x32_bf16(pfh[ks], vhi, acco[nb], 0, 0, 0);
                acco[nb] = __builtin_amdgcn_mfma_f32_16x16x32_bf16(pfh[ks], vlo, acco[nb], 0, 0, 0);
                acco[nb] = __builtin_amdgcn_mfma_f32_16x16x32_bf16(pfl[ks], vhi, acco[nb], 0, 0, 0);
            }
        }

        // rotate graph prefetch
        if (t < 63) {
#pragma unroll
            for (int rg = 0; rg < 4; ++rg)
#pragma unroll
                for (int cb = 0; cb < 4; ++cb)
                    grC[rg][cb] = grN[rg][cb];
        }
    }
#undef STAGE

    // ---- epilogue ----
    const float* bv = bias + head * 64;
#pragma unroll
    for (int rg = 0; rg < 4; ++rg) {
        int row = rowbase + wv * 16 + ln16 * 4 + rg;
        float inv = 1.0f / l_[rg];
#pragma unroll
        for (int nb = 0; nb < 4; ++nb) {
            float v = acco[nb][rg] * inv + bv[nb * 16 + ln15];
            v = v > 0.f ? v : 0.01f * v;
            out[(size_t)(bb * N_NODES + row) * rstride + head * 64 + nb * 16 + ln15] = v;
        }
    }
}

// ---------------------------------------------------------------------------
extern "C" void kernel_launch(void* const* d_in, const int* in_sizes, int n_in,
                              void* d_out, int out_size, void* d_ws, size_t ws_size,
                              hipStream_t stream)
{
    const float* flow = (const float*)d_in[0];
    const float* graph = (const float*)d_in[1];
    const float* w1 = (const float*)d_in[2];
    const float* b1 = (const float*)d_in[3];
    const float* w2 = (const float*)d_in[4];
    const float* b2 = (const float*)d_in[5];
    const float* w3 = (const float*)d_in[6];
    const float* b3 = (const float*)d_in[7];
    const float* Wh = (const float*)d_in[8];
    const float* bh = (const float*)d_in[9];
    const float* Wo = (const float*)d_in[10];
    const float* bo = (const float*)d_in[11];

    char* ws = (char*)d_ws;
    u16* h1_hi  = (u16*)ws;
    u16* h1_lo  = h1_hi + (size_t)8 * 4096 * 64;
    u16* h1T_hi = h1_lo + (size_t)8 * 4096 * 64;
    u16* h1T_lo = h1T_hi + (size_t)8 * 4096 * 64;
    u16* h2_hi  = (u16*)ws;                          // reuse h1 region
    u16* h2_lo  = h2_hi + (size_t)2 * 4096 * 64;
    u16* h2T_hi = h2_lo + (size_t)2 * 4096 * 64;
    u16* h2T_lo = h2T_hi + (size_t)2 * 4096 * 64;
    float* xreg = (float*)(ws + (size_t)4 * 8 * 4096 * 64 * 2);  // x1 / x2 aliased
    float* x1 = xreg;
    float* x2 = xreg;
    float* outp = (float*)d_out;

    hipLaunchKernelGGL(timeblock_kernel, dim3(1024), dim3(192), 0, stream,
                       flow, w1, b1, w2, b2, w3, b3, x1);
    hipLaunchKernelGGL(linear64_split_kernel, dim3(128, 4), dim3(256), 0, stream,
                       x1, Wh, h1_hi, h1_lo, h1T_hi, h1T_lo, 192, 4);
    hipLaunchKernelGGL(flash_mfma_kernel, dim3(64, 8), dim3(256), 0, stream,
                       h1_hi, h1_lo, h1T_hi, h1T_lo, graph, bh, x2, 4, 256);
    hipLaunchKernelGGL(linear64_split_kernel, dim3(128, 1), dim3(256), 0, stream,
                       x2, Wo, h2_hi, h2_lo, h2T_hi, h2T_lo, 256, 1);
    hipLaunchKernelGGL(flash_mfma_kernel, dim3(64, 2), dim3(256), 0, stream,
                       h2_hi, h2_lo, h2T_hi, h2T_lo, graph, bo, outp, 1, 64);
}

// Round 7
// 442.150 us; speedup vs baseline: 3.2764x; 1.4750x over previous
//
#include <hip/hip_runtime.h>
#include <math.h>

#define N_NODES 4096

typedef unsigned short u16;
typedef unsigned int u32;

typedef __attribute__((ext_vector_type(8))) short bfrag;   // 8 bf16 = 4 VGPR
typedef __attribute__((ext_vector_type(4))) float f4;

__device__ __forceinline__ u16 f2bf(float x) {
    union { float f; u32 u; } v; v.f = x;
    u32 r = (v.u + 0x7FFFu + ((v.u >> 16) & 1u)) >> 16;   // RNE
    return (u16)r;
}
__device__ __forceinline__ float bf2f(u16 b) {
    union { float f; u32 u; } v; v.u = ((u32)b) << 16; return v.f;
}

// ---------------------------------------------------------------------------
// wprep: Wcat[k][col], k = kk*192+c, col = conv*64+o, as bf16 hi/mid/lo in
// B^T layout [col][576], per-64-chunk oct XOR swizzle PRE-BAKED so linear
// global_load_lds staging yields the swizzled LDS layout.
// ---------------------------------------------------------------------------
__global__ __launch_bounds__(256) void wprep_kernel(
    const float* __restrict__ w1, const float* __restrict__ w2,
    const float* __restrict__ w3,
    u16* __restrict__ w_hi, u16* __restrict__ w_mid, u16* __restrict__ w_lo)
{
    int idx = blockIdx.x * 256 + threadIdx.x;
    if (idx >= 192 * 576) return;
    int col = idx / 576, k = idx % 576;
    int conv = col >> 6, o = col & 63;
    int kk = k / 192, c = k % 192;
    const float* w = (conv == 0) ? w1 : (conv == 1 ? w2 : w3);
    float v = w[(o * 192 + c) * 3 + kk];
    u16 h = f2bf(v);   float r1 = v - bf2f(h);
    u16 m = f2bf(r1);  float r2 = r1 - bf2f(m);
    u16 lo = f2bf(r2);
    int kc = k >> 6, rem = k & 63, j = rem >> 3, e = rem & 7;
    int pos = col * 576 + kc * 64 + ((j ^ (col & 7)) << 3) + e;
    w_hi[pos] = h;
    w_mid[pos] = m;
    w_lo[pos] = lo;
}

// ---------------------------------------------------------------------------
// timeblock_mfma: x1[node][t*64+o] = relu(c1 + sigmoid(c2) + c3) via
// 3-way-split bf16 MFMA GEMM (6 products -> fp32-exact to ~2^-27 rel).
// Block: 128 nodes x 192 cols, one t; 512 threads = 8 waves as 4(row)x2(col).
// Grid MUST be (8192/128, 3) = (64,3): B*N = 8192 node-rows.  // r6 fix
// ---------------------------------------------------------------------------
__global__ __launch_bounds__(512) void timeblock_mfma_kernel(
    const float* __restrict__ flow,
    const u16* __restrict__ w_hi, const u16* __restrict__ w_mid,
    const u16* __restrict__ w_lo,
    const float* __restrict__ b1, const float* __restrict__ b2,
    const float* __restrict__ b3, float* __restrict__ x1)
{
    __shared__ __align__(16) u16 As[3][128 * 64];    // [hi,mid,lo][row*64 + swz]
    __shared__ __align__(16) u16 Bs[3][192 * 64];    // [hi,mid,lo][col*64 + swz]

    const int tid = threadIdx.x;
    const int wv = tid >> 6, l = tid & 63;
    const int ln15 = l & 15, ln16 = l >> 4;
    const int wr = wv >> 1, wc = wv & 1;             // 4x2 wave grid
    const int nodebase = blockIdx.x * 128;
    const int t = blockIdx.y;

    f4 acc[2][6];
#pragma unroll
    for (int rq = 0; rq < 2; ++rq)
#pragma unroll
        for (int nt = 0; nt < 6; ++nt) {
            acc[rq][nt][0] = 0.f; acc[rq][nt][1] = 0.f;
            acc[rq][nt][2] = 0.f; acc[rq][nt][3] = 0.f;
        }

    for (int kc = 0; kc < 9; ++kc) {
        __syncthreads();   // previous chunk's LDS reads complete

        // ---- stage A: flow fp32 -> bf16 hi/mid/lo, swizzled ds_write ----
#pragma unroll
        for (int u = tid; u < 1024; u += 512) {
            int r = u >> 3, j = u & 7;
            const float* srcp = flow + (size_t)(nodebase + r) * 960 + t * 192 + kc * 64 + j * 8;
            float4 f0 = *(const float4*)srcp;
            float4 f1 = *(const float4*)(srcp + 4);
            float fv[8] = { f0.x, f0.y, f0.z, f0.w, f1.x, f1.y, f1.z, f1.w };
            union { uint4 q; u16 a[8]; } uh, um, ul;
#pragma unroll
            for (int e = 0; e < 8; ++e) {
                u16 h = f2bf(fv[e]);   float r1 = fv[e] - bf2f(h);
                u16 m = f2bf(r1);      float r2 = r1 - bf2f(m);
                uh.a[e] = h; um.a[e] = m; ul.a[e] = f2bf(r2);
            }
            int pos = r * 64 + ((j ^ (r & 7)) << 3);
            *(uint4*)&As[0][pos] = uh.q;
            *(uint4*)&As[1][pos] = um.q;
            *(uint4*)&As[2][pos] = ul.q;
        }

        // ---- stage B: global_load_lds from pre-swizzled weights ----
#pragma unroll
        for (int arr = 0; arr < 3; ++arr) {
            const u16* wsrc = (arr == 0) ? w_hi : (arr == 1 ? w_mid : w_lo);
#pragma unroll
            for (int i = 0; i < 3; ++i) {
                int colg = wv * 24 + i * 8;
                const u16* srcp = wsrc + (size_t)(colg + (l >> 3)) * 576 + kc * 64 + (l & 7) * 8;
                u16* dstp = &Bs[arr][colg * 64];
                __builtin_amdgcn_global_load_lds(
                    (const __attribute__((address_space(1))) u32*)srcp,
                    (__attribute__((address_space(3))) u32*)dstp, 16, 0, 0);
            }
        }

        __syncthreads();   // staging (vm+lgkm) drained

        // ---- A fragments: [rq][term][ks] ----
        bfrag af[2][3][2];
#pragma unroll
        for (int rq = 0; rq < 2; ++rq) {
            int arow = wr * 32 + rq * 16 + ln15;
#pragma unroll
            for (int ks = 0; ks < 2; ++ks) {
                int idx = arow * 64 + (((ks * 4 + ln16) ^ (arow & 7)) << 3);
                af[rq][0][ks] = *(const bfrag*)&As[0][idx];
                af[rq][1][ks] = *(const bfrag*)&As[1][idx];
                af[rq][2][ks] = *(const bfrag*)&As[2][idx];
            }
        }

        // ---- compute: 144 MFMAs per wave (6-product split) ----
#pragma unroll
        for (int cv = 0; cv < 3; ++cv) {
#pragma unroll
            for (int ntj = 0; ntj < 2; ++ntj) {
                int col = cv * 64 + wc * 32 + ntj * 16 + ln15;
                int nt = cv * 2 + ntj;
#pragma unroll
                for (int ks = 0; ks < 2; ++ks) {
                    int idx = col * 64 + (((ks * 4 + ln16) ^ (col & 7)) << 3);
                    bfrag bh = *(const bfrag*)&Bs[0][idx];
                    bfrag bm = *(const bfrag*)&Bs[1][idx];
                    bfrag bl = *(const bfrag*)&Bs[2][idx];
#pragma unroll
                    for (int rq = 0; rq < 2; ++rq) {
                        f4 a = acc[rq][nt];
                        a = __builtin_amdgcn_mfma_f32_16x16x32_bf16(af[rq][0][ks], bh, a, 0, 0, 0);
                        a = __builtin_amdgcn_mfma_f32_16x16x32_bf16(af[rq][0][ks], bm, a, 0, 0, 0);
                        a = __builtin_amdgcn_mfma_f32_16x16x32_bf16(af[rq][1][ks], bh, a, 0, 0, 0);
                        a = __builtin_amdgcn_mfma_f32_16x16x32_bf16(af[rq][0][ks], bl, a, 0, 0, 0);
                        a = __builtin_amdgcn_mfma_f32_16x16x32_bf16(af[rq][2][ks], bh, a, 0, 0, 0);
                        a = __builtin_amdgcn_mfma_f32_16x16x32_bf16(af[rq][1][ks], bm, a, 0, 0, 0);
                        acc[rq][nt] = a;
                    }
                }
            }
        }
    }

    // ---- epilogue: conv combine (lane-local), sigmoid/relu, store ----
#pragma unroll
    for (int rq = 0; rq < 2; ++rq) {
#pragma unroll
        for (int ntj = 0; ntj < 2; ++ntj) {
            int o = wc * 32 + ntj * 16 + ln15;
            float bb1 = b1[o], bb2 = b2[o], bb3 = b3[o];
#pragma unroll
            for (int rg = 0; rg < 4; ++rg) {
                int node = nodebase + wr * 32 + rq * 16 + ln16 * 4 + rg;
                float c1 = acc[rq][0 * 2 + ntj][rg] + bb1;
                float c2 = acc[rq][1 * 2 + ntj][rg] + bb2;
                float c3 = acc[rq][2 * 2 + ntj][rg] + bb3;
                float sg = 1.0f / (1.0f + __expf(-c2));
                float v = c1 + sg + c3;
                x1[(size_t)node * 192 + t * 64 + o] = v > 0.f ? v : 0.f;
            }
        }
    }
}

// ---------------------------------------------------------------------------
// linear64_split: h = in @ W^T per head, emitted as bf16 hi/lo in node-major
// ([map][n][64]) and TILE-BLOCKED feat-major ([map][tile][d][64]) layouts.
// ---------------------------------------------------------------------------
__global__ __launch_bounds__(256) void linear64_split_kernel(
    const float* __restrict__ in, const float* __restrict__ W,
    u16* __restrict__ h_hi, u16* __restrict__ h_lo,
    u16* __restrict__ hTb_hi, u16* __restrict__ hTb_lo,
    int C, int H)
{
    __shared__ float xs[64][68];
    __shared__ float wsm[64][68];
    const int tid = threadIdx.x;
    const int g = blockIdx.y;
    const int rowbase = blockIdx.x * 64;
    const int rgrp = tid >> 4, cgrp = tid & 15;

    float acc[4][4] = {};
    for (int c0 = 0; c0 < C; c0 += 64) {
        __syncthreads();
        for (int i = tid; i < 4096; i += 256) {
            int r = i >> 6, cc = i & 63;
            xs[r][cc]  = in[(size_t)(rowbase + r) * C + c0 + cc];
            wsm[r][cc] = W[(size_t)(g * 64 + r) * C + c0 + cc];
        }
        __syncthreads();
        for (int cc = 0; cc < 64; cc += 4) {
            float4 xv[4], wv[4];
#pragma unroll
            for (int i = 0; i < 4; ++i)
                xv[i] = *reinterpret_cast<const float4*>(&xs[4 * rgrp + i][cc]);
#pragma unroll
            for (int j = 0; j < 4; ++j)
                wv[j] = *reinterpret_cast<const float4*>(&wsm[4 * cgrp + j][cc]);
#pragma unroll
            for (int i = 0; i < 4; ++i) {
#pragma unroll
                for (int j = 0; j < 4; ++j) {
                    acc[i][j] += xv[i].x * wv[j].x + xv[i].y * wv[j].y
                               + xv[i].z * wv[j].z + xv[i].w * wv[j].w;
                }
            }
        }
    }

    u16 hi[4][4], lo[4][4];
#pragma unroll
    for (int i = 0; i < 4; ++i)
#pragma unroll
        for (int j = 0; j < 4; ++j) {
            float a = acc[i][j];
            u16 h = f2bf(a);
            hi[i][j] = h;
            lo[i][j] = f2bf(a - bf2f(h));
        }

    const int b = rowbase >> 12;
    const size_t mapb = (size_t)(b * H + g) * (4096 * 64);

    // node-major [map][n][64]
#pragma unroll
    for (int i = 0; i < 4; ++i) {
        int n = (rowbase & 4095) + 4 * rgrp + i;
        ushort4 vh = { hi[i][0], hi[i][1], hi[i][2], hi[i][3] };
        ushort4 vl = { lo[i][0], lo[i][1], lo[i][2], lo[i][3] };
        *(ushort4*)&h_hi[mapb + (size_t)n * 64 + 4 * cgrp] = vh;
        *(ushort4*)&h_lo[mapb + (size_t)n * 64 + 4 * cgrp] = vl;
    }
    // blocked feat-major [map][tile][d][64]; n0..n0+3 share one tile
    {
        int n0 = (rowbase & 4095) + 4 * rgrp;
        size_t tb = mapb + ((size_t)(n0 >> 6) * 64) * 64;
#pragma unroll
        for (int j = 0; j < 4; ++j) {
            int d = 4 * cgrp + j;
            ushort4 vh = { hi[0][j], hi[1][j], hi[2][j], hi[3][j] };
            ushort4 vl = { lo[0][j], lo[1][j], lo[2][j], lo[3][j] };
            *(ushort4*)&hTb_hi[tb + (size_t)d * 64 + (n0 & 63)] = vh;
            *(ushort4*)&hTb_lo[tb + (size_t)d * 64 + (n0 & 63)] = vl;
        }
    }
}

// ---------------------------------------------------------------------------
// flash_mfma: masked-softmax attention via bf16-split MFMA (round-4 version:
// global_load_lds staging, one barrier/tile, graph prefetch).
// ---------------------------------------------------------------------------
__device__ __forceinline__ float grp16_max(float v) {
    v = fmaxf(v, __shfl_xor(v, 1));
    v = fmaxf(v, __shfl_xor(v, 2));
    v = fmaxf(v, __shfl_xor(v, 4));
    v = fmaxf(v, __shfl_xor(v, 8));
    return v;
}
__device__ __forceinline__ float grp16_sum(float v) {
    v += __shfl_xor(v, 1);
    v += __shfl_xor(v, 2);
    v += __shfl_xor(v, 4);
    v += __shfl_xor(v, 8);
    return v;
}

__global__ __launch_bounds__(256) void flash_mfma_kernel(
    const u16* __restrict__ h_hi, const u16* __restrict__ h_lo,
    const u16* __restrict__ hTb_hi, const u16* __restrict__ hTb_lo,
    const float* __restrict__ graph, const float* __restrict__ bias,
    float* __restrict__ out, int H, int rstride)
{
    __shared__ __align__(16) u16 hcs[2][4][4096];   // [dbuf][hc_hi,hc_lo,V_hi,V_lo]
    __shared__ __align__(16) u16 Ps[2][4096];       // [P_hi, P_lo] (wave-local rows)

    const int tid = threadIdx.x;
    const int wv = tid >> 6;
    const int l = tid & 63;
    const int ln15 = l & 15, ln16 = l >> 4;
    const int by = blockIdx.y;
    const int bb = by / H, head = by % H;
    const size_t mapb = (size_t)by * (4096 * 64);
    const int rowbase = blockIdx.x * 64;

    const int arow = rowbase + wv * 16 + ln15;
    bfrag ahi[2], alo[2];
#pragma unroll
    for (int ks = 0; ks < 2; ++ks) {
        ahi[ks] = *(const bfrag*)(h_hi + mapb + (size_t)arow * 64 + ks * 32 + ln16 * 8);
        alo[ks] = *(const bfrag*)(h_lo + mapb + (size_t)arow * 64 + ks * 32 + ln16 * 8);
    }

    const u16* gA = (wv == 0 ? h_hi : wv == 1 ? h_lo : wv == 2 ? hTb_hi : hTb_lo) + mapb;
    const int lrow = l >> 3;
    const int stoff = lrow * 64 + (((l & 7) ^ lrow) << 3);

#define STAGE(T, BUF)                                                          \
    {                                                                          \
        const u16* srcp = gA + (size_t)(T) * 4096 + stoff;                     \
        u16* dstp = &hcs[BUF][wv][0];                                          \
        _Pragma("unroll")                                                      \
        for (int i_ = 0; i_ < 8; ++i_)                                         \
            __builtin_amdgcn_global_load_lds(                                  \
                (const __attribute__((address_space(1))) u32*)(srcp + i_ * 512), \
                (__attribute__((address_space(3))) u32*)(dstp + i_ * 512),     \
                16, 0, 0);                                                     \
    }

    const float* grow = graph + (size_t)(rowbase + wv * 16 + ln16 * 4) * 4096 + ln15;

    float m_[4], l_[4];
    f4 acco[4];
#pragma unroll
    for (int i = 0; i < 4; ++i) {
        m_[i] = -3.0e38f; l_[i] = 0.f;
        acco[i][0] = 0.f; acco[i][1] = 0.f; acco[i][2] = 0.f; acco[i][3] = 0.f;
    }

    STAGE(0, 0);
    float grC[4][4], grN[4][4];
#pragma unroll
    for (int rg = 0; rg < 4; ++rg)
#pragma unroll
        for (int cb = 0; cb < 4; ++cb)
            grC[rg][cb] = grow[(size_t)rg * 4096 + cb * 16];

    for (int t = 0; t < 64; ++t) {
        const int cur = t & 1;

        __syncthreads();

        if (t < 63) {
            STAGE(t + 1, cur ^ 1);
#pragma unroll
            for (int rg = 0; rg < 4; ++rg)
#pragma unroll
                for (int cb = 0; cb < 4; ++cb)
                    grN[rg][cb] = grow[(size_t)rg * 4096 + (t + 1) * 64 + cb * 16];
        }

        // ---- S phase: 24 MFMAs ----
        f4 accs[4];
#pragma unroll
        for (int cb = 0; cb < 4; ++cb) {
            f4 a; a[0] = 0.f; a[1] = 0.f; a[2] = 0.f; a[3] = 0.f;
#pragma unroll
            for (int ks = 0; ks < 2; ++ks) {
                int c = cb * 16 + ln15;
                int idx = c * 64 + (((ks * 4 + ln16) * 8) ^ ((c & 7) << 3));
                bfrag bhi = *(const bfrag*)&hcs[cur][0][idx];
                bfrag blo = *(const bfrag*)&hcs[cur][1][idx];
                a = __builtin_amdgcn_mfma_f32_16x16x32_bf16(ahi[ks], bhi, a, 0, 0, 0);
                a = __builtin_amdgcn_mfma_f32_16x16x32_bf16(alo[ks], bhi, a, 0, 0, 0);
                a = __builtin_amdgcn_mfma_f32_16x16x32_bf16(ahi[ks], blo, a, 0, 0, 0);
            }
            accs[cb] = a;
        }

        // ---- mask + online softmax; write P hi/lo ----
#pragma unroll
        for (int rg = 0; rg < 4; ++rg) {
            float vs[4];
#pragma unroll
            for (int cb = 0; cb < 4; ++cb) {
                float v = accs[cb][rg] * grC[rg][cb];
                vs[cb] = (v == 0.f) ? -1e16f : v;
            }
            float tm = fmaxf(fmaxf(vs[0], vs[1]), fmaxf(vs[2], vs[3]));
            tm = grp16_max(tm);
            float mn = fmaxf(m_[rg], tm);
            float corr = __expf(m_[rg] - mn);
            float p[4];
            p[0] = __expf(vs[0] - mn);
            p[1] = __expf(vs[1] - mn);
            p[2] = __expf(vs[2] - mn);
            p[3] = __expf(vs[3] - mn);
            float rs = grp16_sum(p[0] + p[1] + p[2] + p[3]);
            l_[rg] = l_[rg] * corr + rs;
            m_[rg] = mn;
#pragma unroll
            for (int nb = 0; nb < 4; ++nb) acco[nb][rg] *= corr;

            int prow = wv * 16 + ln16 * 4 + rg;
            int psw = (prow & 7) << 3;
#pragma unroll
            for (int cb = 0; cb < 4; ++cb) {
                int idx = prow * 64 + ((cb * 16 + ln15) ^ psw);
                u16 ph = f2bf(p[cb]);
                Ps[0][idx] = ph;
                Ps[1][idx] = f2bf(p[cb] - bf2f(ph));
            }
        }

        // ---- PV phase: 24 MFMAs ----
        bfrag pfh[2], pfl[2];
#pragma unroll
        for (int ks = 0; ks < 2; ++ks) {
            int pr = wv * 16 + ln15;
            int idx = pr * 64 + (((ks * 4 + ln16) * 8) ^ ((pr & 7) << 3));
            pfh[ks] = *(const bfrag*)&Ps[0][idx];
            pfl[ks] = *(const bfrag*)&Ps[1][idx];
        }
#pragma unroll
        for (int nb = 0; nb < 4; ++nb) {
#pragma unroll
            for (int ks = 0; ks < 2; ++ks) {
                int nr = nb * 16 + ln15;
                int idx = nr * 64 + (((ks * 4 + ln16) * 8) ^ ((nr & 7) << 3));
                bfrag vhi = *(const bfrag*)&hcs[cur][2][idx];
                bfrag vlo = *(const bfrag*)&hcs[cur][3][idx];
                acco[nb] = __builtin_amdgcn_mfma_f32_16x16x32_bf16(pfh[ks], vhi, acco[nb], 0, 0, 0);
                acco[nb] = __builtin_amdgcn_mfma_f32_16x16x32_bf16(pfh[ks], vlo, acco[nb], 0, 0, 0);
                acco[nb] = __builtin_amdgcn_mfma_f32_16x16x32_bf16(pfl[ks], vhi, acco[nb], 0, 0, 0);
            }
        }

        if (t < 63) {
#pragma unroll
            for (int rg = 0; rg < 4; ++rg)
#pragma unroll
                for (int cb = 0; cb < 4; ++cb)
                    grC[rg][cb] = grN[rg][cb];
        }
    }
#undef STAGE

    const float* bv = bias + head * 64;
#pragma unroll
    for (int rg = 0; rg < 4; ++rg) {
        int row = rowbase + wv * 16 + ln16 * 4 + rg;
        float inv = 1.0f / l_[rg];
#pragma unroll
        for (int nb = 0; nb < 4; ++nb) {
            float v = acco[nb][rg] * inv + bv[nb * 16 + ln15];
            v = v > 0.f ? v : 0.01f * v;
            out[(size_t)(bb * N_NODES + row) * rstride + head * 64 + nb * 16 + ln15] = v;
        }
    }
}

// ---------------------------------------------------------------------------
extern "C" void kernel_launch(void* const* d_in, const int* in_sizes, int n_in,
                              void* d_out, int out_size, void* d_ws, size_t ws_size,
                              hipStream_t stream)
{
    const float* flow = (const float*)d_in[0];
    const float* graph = (const float*)d_in[1];
    const float* w1 = (const float*)d_in[2];
    const float* b1 = (const float*)d_in[3];
    const float* w2 = (const float*)d_in[4];
    const float* b2 = (const float*)d_in[5];
    const float* w3 = (const float*)d_in[6];
    const float* b3 = (const float*)d_in[7];
    const float* Wh = (const float*)d_in[8];
    const float* bh = (const float*)d_in[9];
    const float* Wo = (const float*)d_in[10];
    const float* bo = (const float*)d_in[11];

    char* ws = (char*)d_ws;
    // weight-prep region aliases the h1 region (free until linear64 runs)
    u16* wc_hi  = (u16*)ws;                          // 192*576 u16 each
    u16* wc_mid = wc_hi + (size_t)192 * 576;
    u16* wc_lo  = wc_mid + (size_t)192 * 576;

    u16* h1_hi  = (u16*)ws;
    u16* h1_lo  = h1_hi + (size_t)8 * 4096 * 64;
    u16* h1T_hi = h1_lo + (size_t)8 * 4096 * 64;
    u16* h1T_lo = h1T_hi + (size_t)8 * 4096 * 64;
    u16* h2_hi  = (u16*)ws;                          // reuse h1 region
    u16* h2_lo  = h2_hi + (size_t)2 * 4096 * 64;
    u16* h2T_hi = h2_lo + (size_t)2 * 4096 * 64;
    u16* h2T_lo = h2T_hi + (size_t)2 * 4096 * 64;
    float* xreg = (float*)(ws + (size_t)4 * 8 * 4096 * 64 * 2);  // x1 / x2 aliased
    float* x1 = xreg;
    float* x2 = xreg;
    float* outp = (float*)d_out;

    hipLaunchKernelGGL(wprep_kernel, dim3(432), dim3(256), 0, stream,
                       w1, w2, w3, wc_hi, wc_mid, wc_lo);
    hipLaunchKernelGGL(timeblock_mfma_kernel, dim3(64, 3), dim3(512), 0, stream,
                       flow, wc_hi, wc_mid, wc_lo, b1, b2, b3, x1);
    hipLaunchKernelGGL(linear64_split_kernel, dim3(128, 4), dim3(256), 0, stream,
                       x1, Wh, h1_hi, h1_lo, h1T_hi, h1T_lo, 192, 4);
    hipLaunchKernelGGL(flash_mfma_kernel, dim3(64, 8), dim3(256), 0, stream,
                       h1_hi, h1_lo, h1T_hi, h1T_lo, graph, bh, x2, 4, 256);
    hipLaunchKernelGGL(linear64_split_kernel, dim3(128, 1), dim3(256), 0, stream,
                       x2, Wo, h2_hi, h2_lo, h2T_hi, h2T_lo, 256, 1);
    hipLaunchKernelGGL(flash_mfma_kernel, dim3(64, 2), dim3(256), 0, stream,
                       h2_hi, h2_lo, h2T_hi, h2T_lo, graph, bo, outp, 1, 64);
}

// Round 8
// 410.132 us; speedup vs baseline: 3.5322x; 1.0781x over previous
//
#include <hip/hip_runtime.h>
#include <math.h>

#define N_NODES 4096

typedef unsigned short u16;
typedef unsigned int u32;

typedef __attribute__((ext_vector_type(8))) short bfrag;   // 8 bf16 = 4 VGPR
typedef __attribute__((ext_vector_type(4))) float f4;

__device__ __forceinline__ u16 f2bf(float x) {
    union { float f; u32 u; } v; v.f = x;
    u32 r = (v.u + 0x7FFFu + ((v.u >> 16) & 1u)) >> 16;   // RNE
    return (u16)r;
}
__device__ __forceinline__ float bf2f(u16 b) {
    union { float f; u32 u; } v; v.u = ((u32)b) << 16; return v.f;
}
__device__ __forceinline__ u32 cvtpk(float a, float b) {   // lo16=bf16(a), hi16=bf16(b)
    u32 r;
    asm("v_cvt_pk_bf16_f32 %0, %1, %2" : "=v"(r) : "v"(a), "v"(b));
    return r;
}
__device__ __forceinline__ float u2f(u32 u) {
    union { u32 u; float f; } v; v.u = u; return v.f;
}

// ---------------------------------------------------------------------------
// wprep: Wcat[k][col] as bf16 hi/mid/lo in B^T layout [col][576], swizzled.
// ---------------------------------------------------------------------------
__global__ __launch_bounds__(256) void wprep_kernel(
    const float* __restrict__ w1, const float* __restrict__ w2,
    const float* __restrict__ w3,
    u16* __restrict__ w_hi, u16* __restrict__ w_mid, u16* __restrict__ w_lo)
{
    int idx = blockIdx.x * 256 + threadIdx.x;
    if (idx >= 192 * 576) return;
    int col = idx / 576, k = idx % 576;
    int conv = col >> 6, o = col & 63;
    int kk = k / 192, c = k % 192;
    const float* w = (conv == 0) ? w1 : (conv == 1 ? w2 : w3);
    float v = w[(o * 192 + c) * 3 + kk];
    u16 h = f2bf(v);   float r1 = v - bf2f(h);
    u16 m = f2bf(r1);  float r2 = r1 - bf2f(m);
    u16 lo = f2bf(r2);
    int kc = k >> 6, rem = k & 63, j = rem >> 3, e = rem & 7;
    int pos = col * 576 + kc * 64 + ((j ^ (col & 7)) << 3) + e;
    w_hi[pos] = h;
    w_mid[pos] = m;
    w_lo[pos] = lo;
}

// ---------------------------------------------------------------------------
// timeblock_mfma (round-6, passing): 3-way-split bf16 MFMA GEMM.
// ---------------------------------------------------------------------------
__global__ __launch_bounds__(512) void timeblock_mfma_kernel(
    const float* __restrict__ flow,
    const u16* __restrict__ w_hi, const u16* __restrict__ w_mid,
    const u16* __restrict__ w_lo,
    const float* __restrict__ b1, const float* __restrict__ b2,
    const float* __restrict__ b3, float* __restrict__ x1)
{
    __shared__ __align__(16) u16 As[3][128 * 64];
    __shared__ __align__(16) u16 Bs[3][192 * 64];

    const int tid = threadIdx.x;
    const int wv = tid >> 6, l = tid & 63;
    const int ln15 = l & 15, ln16 = l >> 4;
    const int wr = wv >> 1, wc = wv & 1;
    const int nodebase = blockIdx.x * 128;
    const int t = blockIdx.y;

    f4 acc[2][6];
#pragma unroll
    for (int rq = 0; rq < 2; ++rq)
#pragma unroll
        for (int nt = 0; nt < 6; ++nt) {
            acc[rq][nt][0] = 0.f; acc[rq][nt][1] = 0.f;
            acc[rq][nt][2] = 0.f; acc[rq][nt][3] = 0.f;
        }

    for (int kc = 0; kc < 9; ++kc) {
        __syncthreads();

#pragma unroll
        for (int u = tid; u < 1024; u += 512) {
            int r = u >> 3, j = u & 7;
            const float* srcp = flow + (size_t)(nodebase + r) * 960 + t * 192 + kc * 64 + j * 8;
            float4 f0 = *(const float4*)srcp;
            float4 f1 = *(const float4*)(srcp + 4);
            float fv[8] = { f0.x, f0.y, f0.z, f0.w, f1.x, f1.y, f1.z, f1.w };
            union { uint4 q; u16 a[8]; } uh, um, ul;
#pragma unroll
            for (int e = 0; e < 8; ++e) {
                u16 h = f2bf(fv[e]);   float r1 = fv[e] - bf2f(h);
                u16 m = f2bf(r1);      float r2 = r1 - bf2f(m);
                uh.a[e] = h; um.a[e] = m; ul.a[e] = f2bf(r2);
            }
            int pos = r * 64 + ((j ^ (r & 7)) << 3);
            *(uint4*)&As[0][pos] = uh.q;
            *(uint4*)&As[1][pos] = um.q;
            *(uint4*)&As[2][pos] = ul.q;
        }

#pragma unroll
        for (int arr = 0; arr < 3; ++arr) {
            const u16* wsrc = (arr == 0) ? w_hi : (arr == 1 ? w_mid : w_lo);
#pragma unroll
            for (int i = 0; i < 3; ++i) {
                int colg = wv * 24 + i * 8;
                const u16* srcp = wsrc + (size_t)(colg + (l >> 3)) * 576 + kc * 64 + (l & 7) * 8;
                u16* dstp = &Bs[arr][colg * 64];
                __builtin_amdgcn_global_load_lds(
                    (const __attribute__((address_space(1))) u32*)srcp,
                    (__attribute__((address_space(3))) u32*)dstp, 16, 0, 0);
            }
        }

        __syncthreads();

        bfrag af[2][3][2];
#pragma unroll
        for (int rq = 0; rq < 2; ++rq) {
            int arow = wr * 32 + rq * 16 + ln15;
#pragma unroll
            for (int ks = 0; ks < 2; ++ks) {
                int idx = arow * 64 + (((ks * 4 + ln16) ^ (arow & 7)) << 3);
                af[rq][0][ks] = *(const bfrag*)&As[0][idx];
                af[rq][1][ks] = *(const bfrag*)&As[1][idx];
                af[rq][2][ks] = *(const bfrag*)&As[2][idx];
            }
        }

#pragma unroll
        for (int cv = 0; cv < 3; ++cv) {
#pragma unroll
            for (int ntj = 0; ntj < 2; ++ntj) {
                int col = cv * 64 + wc * 32 + ntj * 16 + ln15;
                int nt = cv * 2 + ntj;
#pragma unroll
                for (int ks = 0; ks < 2; ++ks) {
                    int idx = col * 64 + (((ks * 4 + ln16) ^ (col & 7)) << 3);
                    bfrag bh = *(const bfrag*)&Bs[0][idx];
                    bfrag bm = *(const bfrag*)&Bs[1][idx];
                    bfrag bl = *(const bfrag*)&Bs[2][idx];
#pragma unroll
                    for (int rq = 0; rq < 2; ++rq) {
                        f4 a = acc[rq][nt];
                        a = __builtin_amdgcn_mfma_f32_16x16x32_bf16(af[rq][0][ks], bh, a, 0, 0, 0);
                        a = __builtin_amdgcn_mfma_f32_16x16x32_bf16(af[rq][0][ks], bm, a, 0, 0, 0);
                        a = __builtin_amdgcn_mfma_f32_16x16x32_bf16(af[rq][1][ks], bh, a, 0, 0, 0);
                        a = __builtin_amdgcn_mfma_f32_16x16x32_bf16(af[rq][0][ks], bl, a, 0, 0, 0);
                        a = __builtin_amdgcn_mfma_f32_16x16x32_bf16(af[rq][2][ks], bh, a, 0, 0, 0);
                        a = __builtin_amdgcn_mfma_f32_16x16x32_bf16(af[rq][1][ks], bm, a, 0, 0, 0);
                        acc[rq][nt] = a;
                    }
                }
            }
        }
    }

#pragma unroll
    for (int rq = 0; rq < 2; ++rq) {
#pragma unroll
        for (int ntj = 0; ntj < 2; ++ntj) {
            int o = wc * 32 + ntj * 16 + ln15;
            float bb1 = b1[o], bb2 = b2[o], bb3 = b3[o];
#pragma unroll
            for (int rg = 0; rg < 4; ++rg) {
                int node = nodebase + wr * 32 + rq * 16 + ln16 * 4 + rg;
                float c1 = acc[rq][0 * 2 + ntj][rg] + bb1;
                float c2 = acc[rq][1 * 2 + ntj][rg] + bb2;
                float c3 = acc[rq][2 * 2 + ntj][rg] + bb3;
                float sg = 1.0f / (1.0f + __expf(-c2));
                float v = c1 + sg + c3;
                x1[(size_t)node * 192 + t * 64 + o] = v > 0.f ? v : 0.f;
            }
        }
    }
}

// ---------------------------------------------------------------------------
// linear64_split (round-4, passing)
// ---------------------------------------------------------------------------
__global__ __launch_bounds__(256) void linear64_split_kernel(
    const float* __restrict__ in, const float* __restrict__ W,
    u16* __restrict__ h_hi, u16* __restrict__ h_lo,
    u16* __restrict__ hTb_hi, u16* __restrict__ hTb_lo,
    int C, int H)
{
    __shared__ float xs[64][68];
    __shared__ float wsm[64][68];
    const int tid = threadIdx.x;
    const int g = blockIdx.y;
    const int rowbase = blockIdx.x * 64;
    const int rgrp = tid >> 4, cgrp = tid & 15;

    float acc[4][4] = {};
    for (int c0 = 0; c0 < C; c0 += 64) {
        __syncthreads();
        for (int i = tid; i < 4096; i += 256) {
            int r = i >> 6, cc = i & 63;
            xs[r][cc]  = in[(size_t)(rowbase + r) * C + c0 + cc];
            wsm[r][cc] = W[(size_t)(g * 64 + r) * C + c0 + cc];
        }
        __syncthreads();
        for (int cc = 0; cc < 64; cc += 4) {
            float4 xv[4], wv[4];
#pragma unroll
            for (int i = 0; i < 4; ++i)
                xv[i] = *reinterpret_cast<const float4*>(&xs[4 * rgrp + i][cc]);
#pragma unroll
            for (int j = 0; j < 4; ++j)
                wv[j] = *reinterpret_cast<const float4*>(&wsm[4 * cgrp + j][cc]);
#pragma unroll
            for (int i = 0; i < 4; ++i) {
#pragma unroll
                for (int j = 0; j < 4; ++j) {
                    acc[i][j] += xv[i].x * wv[j].x + xv[i].y * wv[j].y
                               + xv[i].z * wv[j].z + xv[i].w * wv[j].w;
                }
            }
        }
    }

    u16 hi[4][4], lo[4][4];
#pragma unroll
    for (int i = 0; i < 4; ++i)
#pragma unroll
        for (int j = 0; j < 4; ++j) {
            float a = acc[i][j];
            u16 h = f2bf(a);
            hi[i][j] = h;
            lo[i][j] = f2bf(a - bf2f(h));
        }

    const int b = rowbase >> 12;
    const size_t mapb = (size_t)(b * H + g) * (4096 * 64);

#pragma unroll
    for (int i = 0; i < 4; ++i) {
        int n = (rowbase & 4095) + 4 * rgrp + i;
        ushort4 vh = { hi[i][0], hi[i][1], hi[i][2], hi[i][3] };
        ushort4 vl = { lo[i][0], lo[i][1], lo[i][2], lo[i][3] };
        *(ushort4*)&h_hi[mapb + (size_t)n * 64 + 4 * cgrp] = vh;
        *(ushort4*)&h_lo[mapb + (size_t)n * 64 + 4 * cgrp] = vl;
    }
    {
        int n0 = (rowbase & 4095) + 4 * rgrp;
        size_t tb = mapb + ((size_t)(n0 >> 6) * 64) * 64;
#pragma unroll
        for (int j = 0; j < 4; ++j) {
            int d = 4 * cgrp + j;
            ushort4 vh = { hi[0][j], hi[1][j], hi[2][j], hi[3][j] };
            ushort4 vl = { lo[0][j], lo[1][j], lo[2][j], lo[3][j] };
            *(ushort4*)&hTb_hi[tb + (size_t)d * 64 + (n0 & 63)] = vh;
            *(ushort4*)&hTb_lo[tb + (size_t)d * 64 + (n0 & 63)] = vl;
        }
    }
}

// ---------------------------------------------------------------------------
// flash_mfma (round-8): swapped QK^T (S^T via mfma arg swap) -> per-thread
// row softmax (15 in-reg ops + 2 shfl); cvt_pk bf16 P conversion; b64 P
// stores; float4 graph loads; setprio around MFMA clusters.
// ---------------------------------------------------------------------------
__global__ __launch_bounds__(256) void flash_mfma_kernel(
    const u16* __restrict__ h_hi, const u16* __restrict__ h_lo,
    const u16* __restrict__ hTb_hi, const u16* __restrict__ hTb_lo,
    const float* __restrict__ graph, const float* __restrict__ bias,
    float* __restrict__ out, int H, int rstride)
{
    __shared__ __align__(16) u16 hcs[2][4][4096];   // [dbuf][K_hi,K_lo,V_hi,V_lo]
    __shared__ __align__(16) u16 Ps[2][4096];       // [P_hi, P_lo] (wave-local rows)

    const int tid = threadIdx.x;
    const int wv = tid >> 6;
    const int l = tid & 63;
    const int ln15 = l & 15, ln16 = l >> 4;
    const int by = blockIdx.y;
    const int bb = by / H, head = by % H;
    const size_t mapb = (size_t)by * (4096 * 64);
    const int rowbase = blockIdx.x * 64;

    // hr fragments (B-operand of swapped S^T): lane ln15 = q-row
    const int arow = rowbase + wv * 16 + ln15;
    bfrag ahi[2], alo[2];
#pragma unroll
    for (int ks = 0; ks < 2; ++ks) {
        ahi[ks] = *(const bfrag*)(h_hi + mapb + (size_t)arow * 64 + ks * 32 + ln16 * 8);
        alo[ks] = *(const bfrag*)(h_lo + mapb + (size_t)arow * 64 + ks * 32 + ln16 * 8);
    }

    const u16* gA = (wv == 0 ? h_hi : wv == 1 ? h_lo : wv == 2 ? hTb_hi : hTb_lo) + mapb;
    const int lrow = l >> 3;
    const int stoff = lrow * 64 + (((l & 7) ^ lrow) << 3);

#define STAGE(T, BUF)                                                          \
    {                                                                          \
        const u16* srcp = gA + (size_t)(T) * 4096 + stoff;                     \
        u16* dstp = &hcs[BUF][wv][0];                                          \
        _Pragma("unroll")                                                      \
        for (int i_ = 0; i_ < 8; ++i_)                                         \
            __builtin_amdgcn_global_load_lds(                                  \
                (const __attribute__((address_space(1))) u32*)(srcp + i_ * 512), \
                (__attribute__((address_space(3))) u32*)(dstp + i_ * 512),     \
                16, 0, 0);                                                     \
    }

    // swapped-S mask access: thread owns q-row ln15, cols cb*16 + ln16*4 + j
    const float* grow = graph + (size_t)(rowbase + wv * 16 + ln15) * 4096 + ln16 * 4;

    float m_ = -3.0e38f, l_ = 0.f;
    f4 acco[4];
#pragma unroll
    for (int i = 0; i < 4; ++i) {
        acco[i][0] = 0.f; acco[i][1] = 0.f; acco[i][2] = 0.f; acco[i][3] = 0.f;
    }

    STAGE(0, 0);
    float4 grC[4], grN[4];
#pragma unroll
    for (int cb = 0; cb < 4; ++cb)
        grC[cb] = *(const float4*)(grow + cb * 16);

    for (int t = 0; t < 64; ++t) {
        const int cur = t & 1;

        __syncthreads();

        if (t < 63) {
            STAGE(t + 1, cur ^ 1);
#pragma unroll
            for (int cb = 0; cb < 4; ++cb)
                grN[cb] = *(const float4*)(grow + (t + 1) * 64 + cb * 16);
        }

        // ---- S^T phase: 24 MFMAs (swapped args) ----
        __builtin_amdgcn_s_setprio(1);
        f4 accs[4];
#pragma unroll
        for (int cb = 0; cb < 4; ++cb) {
            f4 a; a[0] = 0.f; a[1] = 0.f; a[2] = 0.f; a[3] = 0.f;
#pragma unroll
            for (int ks = 0; ks < 2; ++ks) {
                int c = cb * 16 + ln15;
                int idx = c * 64 + (((ks * 4 + ln16) * 8) ^ ((c & 7) << 3));
                bfrag bhi = *(const bfrag*)&hcs[cur][0][idx];
                bfrag blo = *(const bfrag*)&hcs[cur][1][idx];
                a = __builtin_amdgcn_mfma_f32_16x16x32_bf16(bhi, ahi[ks], a, 0, 0, 0);
                a = __builtin_amdgcn_mfma_f32_16x16x32_bf16(bhi, alo[ks], a, 0, 0, 0);
                a = __builtin_amdgcn_mfma_f32_16x16x32_bf16(blo, ahi[ks], a, 0, 0, 0);
            }
            accs[cb] = a;
        }
        __builtin_amdgcn_s_setprio(0);

        // ---- mask (thread-local row) ----
        float p[4][4];
#pragma unroll
        for (int cb = 0; cb < 4; ++cb) {
            float g0 = grC[cb].x, g1 = grC[cb].y, g2 = grC[cb].z, g3 = grC[cb].w;
            float v0 = accs[cb][0] * g0; p[cb][0] = (v0 == 0.f) ? -1e16f : v0;
            float v1 = accs[cb][1] * g1; p[cb][1] = (v1 == 0.f) ? -1e16f : v1;
            float v2 = accs[cb][2] * g2; p[cb][2] = (v2 == 0.f) ? -1e16f : v2;
            float v3 = accs[cb][3] * g3; p[cb][3] = (v3 == 0.f) ? -1e16f : v3;
        }

        // ---- row max: 15 in-thread + 2 shfl ----
        float tm = fmaxf(fmaxf(p[0][0], p[0][1]), fmaxf(p[0][2], p[0][3]));
#pragma unroll
        for (int cb = 1; cb < 4; ++cb)
            tm = fmaxf(tm, fmaxf(fmaxf(p[cb][0], p[cb][1]), fmaxf(p[cb][2], p[cb][3])));
        tm = fmaxf(tm, __shfl_xor(tm, 16));
        tm = fmaxf(tm, __shfl_xor(tm, 32));

        float mn = fmaxf(m_, tm);
        float corr = __expf(m_ - mn);

        // ---- exp + row sum ----
        float rs = 0.f;
#pragma unroll
        for (int cb = 0; cb < 4; ++cb) {
            p[cb][0] = __expf(p[cb][0] - mn);
            p[cb][1] = __expf(p[cb][1] - mn);
            p[cb][2] = __expf(p[cb][2] - mn);
            p[cb][3] = __expf(p[cb][3] - mn);
            rs += (p[cb][0] + p[cb][1]) + (p[cb][2] + p[cb][3]);
        }
        rs += __shfl_xor(rs, 16);
        rs += __shfl_xor(rs, 32);
        l_ = l_ * corr + rs;
        m_ = mn;

        // ---- rescale O (acc rows are ln16*4+rg -> fetch corr via shfl) ----
        float corr4[4];
#pragma unroll
        for (int rg = 0; rg < 4; ++rg)
            corr4[rg] = __shfl(corr, ln16 * 4 + rg);
#pragma unroll
        for (int nb = 0; nb < 4; ++nb) {
            acco[nb][0] *= corr4[0]; acco[nb][1] *= corr4[1];
            acco[nb][2] *= corr4[2]; acco[nb][3] *= corr4[3];
        }

        // ---- P pack (cvt_pk) + b64 swizzled stores ----
        {
            int prow = wv * 16 + ln15;
            int psw = prow & 7;
#pragma unroll
            for (int cb = 0; cb < 4; ++cb) {
                u32 uh0 = cvtpk(p[cb][0], p[cb][1]);
                u32 uh1 = cvtpk(p[cb][2], p[cb][3]);
                float h0 = u2f(uh0 << 16), h1 = u2f(uh0 & 0xffff0000u);
                float h2 = u2f(uh1 << 16), h3 = u2f(uh1 & 0xffff0000u);
                u32 ul0 = cvtpk(p[cb][0] - h0, p[cb][1] - h1);
                u32 ul1 = cvtpk(p[cb][2] - h2, p[cb][3] - h3);
                int c = cb * 16 + ln16 * 4;
                int idx = prow * 64 + (((c >> 3) ^ psw) << 3) + (c & 7);
                uint2 vh = { uh0, uh1 };
                uint2 vl = { ul0, ul1 };
                *(uint2*)&Ps[0][idx] = vh;
                *(uint2*)&Ps[1][idx] = vl;
            }
        }

        // ---- PV phase: 24 MFMAs (unchanged layout) ----
        bfrag pfh[2], pfl[2];
#pragma unroll
        for (int ks = 0; ks < 2; ++ks) {
            int pr = wv * 16 + ln15;
            int idx = pr * 64 + (((ks * 4 + ln16) * 8) ^ ((pr & 7) << 3));
            pfh[ks] = *(const bfrag*)&Ps[0][idx];
            pfl[ks] = *(const bfrag*)&Ps[1][idx];
        }
        __builtin_amdgcn_s_setprio(1);
#pragma unroll
        for (int nb = 0; nb < 4; ++nb) {
#pragma unroll
            for (int ks = 0; ks < 2; ++ks) {
                int nr = nb * 16 + ln15;
                int idx = nr * 64 + (((ks * 4 + ln16) * 8) ^ ((nr & 7) << 3));
                bfrag vhi = *(const bfrag*)&hcs[cur][2][idx];
                bfrag vlo = *(const bfrag*)&hcs[cur][3][idx];
                acco[nb] = __builtin_amdgcn_mfma_f32_16x16x32_bf16(pfh[ks], vhi, acco[nb], 0, 0, 0);
                acco[nb] = __builtin_amdgcn_mfma_f32_16x16x32_bf16(pfh[ks], vlo, acco[nb], 0, 0, 0);
                acco[nb] = __builtin_amdgcn_mfma_f32_16x16x32_bf16(pfl[ks], vhi, acco[nb], 0, 0, 0);
            }
        }
        __builtin_amdgcn_s_setprio(0);

        if (t < 63) {
#pragma unroll
            for (int cb = 0; cb < 4; ++cb)
                grC[cb] = grN[cb];
        }
    }
#undef STAGE

    // ---- epilogue: acc rows ln16*4+rg -> fetch l via shfl ----
    float l4[4];
#pragma unroll
    for (int rg = 0; rg < 4; ++rg)
        l4[rg] = __shfl(l_, ln16 * 4 + rg);

    const float* bv = bias + head * 64;
#pragma unroll
    for (int rg = 0; rg < 4; ++rg) {
        int row = rowbase + wv * 16 + ln16 * 4 + rg;
        float inv = 1.0f / l4[rg];
#pragma unroll
        for (int nb = 0; nb < 4; ++nb) {
            float v = acco[nb][rg] * inv + bv[nb * 16 + ln15];
            v = v > 0.f ? v : 0.01f * v;
            out[(size_t)(bb * N_NODES + row) * rstride + head * 64 + nb * 16 + ln15] = v;
        }
    }
}

// ---------------------------------------------------------------------------
extern "C" void kernel_launch(void* const* d_in, const int* in_sizes, int n_in,
                              void* d_out, int out_size, void* d_ws, size_t ws_size,
                              hipStream_t stream)
{
    const float* flow = (const float*)d_in[0];
    const float* graph = (const float*)d_in[1];
    const float* w1 = (const float*)d_in[2];
    const float* b1 = (const float*)d_in[3];
    const float* w2 = (const float*)d_in[4];
    const float* b2 = (const float*)d_in[5];
    const float* w3 = (const float*)d_in[6];
    const float* b3 = (const float*)d_in[7];
    const float* Wh = (const float*)d_in[8];
    const float* bh = (const float*)d_in[9];
    const float* Wo = (const float*)d_in[10];
    const float* bo = (const float*)d_in[11];

    char* ws = (char*)d_ws;
    u16* wc_hi  = (u16*)ws;                          // aliases h1 region
    u16* wc_mid = wc_hi + (size_t)192 * 576;
    u16* wc_lo  = wc_mid + (size_t)192 * 576;

    u16* h1_hi  = (u16*)ws;
    u16* h1_lo  = h1_hi + (size_t)8 * 4096 * 64;
    u16* h1T_hi = h1_lo + (size_t)8 * 4096 * 64;
    u16* h1T_lo = h1T_hi + (size_t)8 * 4096 * 64;
    u16* h2_hi  = (u16*)ws;
    u16* h2_lo  = h2_hi + (size_t)2 * 4096 * 64;
    u16* h2T_hi = h2_lo + (size_t)2 * 4096 * 64;
    u16* h2T_lo = h2T_hi + (size_t)2 * 4096 * 64;
    float* xreg = (float*)(ws + (size_t)4 * 8 * 4096 * 64 * 2);
    float* x1 = xreg;
    float* x2 = xreg;
    float* outp = (float*)d_out;

    hipLaunchKernelGGL(wprep_kernel, dim3(432), dim3(256), 0, stream,
                       w1, w2, w3, wc_hi, wc_mid, wc_lo);
    hipLaunchKernelGGL(timeblock_mfma_kernel, dim3(64, 3), dim3(512), 0, stream,
                       flow, wc_hi, wc_mid, wc_lo, b1, b2, b3, x1);
    hipLaunchKernelGGL(linear64_split_kernel, dim3(128, 4), dim3(256), 0, stream,
                       x1, Wh, h1_hi, h1_lo, h1T_hi, h1T_lo, 192, 4);
    hipLaunchKernelGGL(flash_mfma_kernel, dim3(64, 8), dim3(256), 0, stream,
                       h1_hi, h1_lo, h1T_hi, h1T_lo, graph, bh, x2, 4, 256);
    hipLaunchKernelGGL(linear64_split_kernel, dim3(128, 1), dim3(256), 0, stream,
                       x2, Wo, h2_hi, h2_lo, h2T_hi, h2T_lo, 256, 1);
    hipLaunchKernelGGL(flash_mfma_kernel, dim3(64, 2), dim3(256), 0, stream,
                       h2_hi, h2_lo, h2T_hi, h2T_lo, graph, bo, outp, 1, 64);
}

// Round 9
// 324.498 us; speedup vs baseline: 4.4644x; 1.2639x over previous
//
#include <hip/hip_runtime.h>
#include <math.h>

#define N_NODES 4096

typedef unsigned short u16;
typedef unsigned int u32;

typedef __attribute__((ext_vector_type(8))) short bfrag;   // 8 bf16 = 4 VGPR
typedef __attribute__((ext_vector_type(4))) float f4;

__device__ __forceinline__ u16 f2bf(float x) {
    union { float f; u32 u; } v; v.f = x;
    u32 r = (v.u + 0x7FFFu + ((v.u >> 16) & 1u)) >> 16;   // RNE
    return (u16)r;
}
__device__ __forceinline__ float bf2f(u16 b) {
    union { float f; u32 u; } v; v.u = ((u32)b) << 16; return v.f;
}
__device__ __forceinline__ u32 cvtpk(float a, float b) {   // lo16=bf16(a), hi16=bf16(b)
    u32 r;
    asm("v_cvt_pk_bf16_f32 %0, %1, %2" : "=v"(r) : "v"(a), "v"(b));
    return r;
}
__device__ __forceinline__ float u2f(u32 u) {
    union { u32 u; float f; } v; v.u = u; return v.f;
}

// ---------------------------------------------------------------------------
// wprep: Wcat[k][col] as bf16 hi/mid/lo in B^T layout [col][576], swizzled.
// ---------------------------------------------------------------------------
__global__ __launch_bounds__(256) void wprep_kernel(
    const float* __restrict__ w1, const float* __restrict__ w2,
    const float* __restrict__ w3,
    u16* __restrict__ w_hi, u16* __restrict__ w_mid, u16* __restrict__ w_lo)
{
    int idx = blockIdx.x * 256 + threadIdx.x;
    if (idx >= 192 * 576) return;
    int col = idx / 576, k = idx % 576;
    int conv = col >> 6, o = col & 63;
    int kk = k / 192, c = k % 192;
    const float* w = (conv == 0) ? w1 : (conv == 1 ? w2 : w3);
    float v = w[(o * 192 + c) * 3 + kk];
    u16 h = f2bf(v);   float r1 = v - bf2f(h);
    u16 m = f2bf(r1);  float r2 = r1 - bf2f(m);
    u16 lo = f2bf(r2);
    int kc = k >> 6, rem = k & 63, j = rem >> 3, e = rem & 7;
    int pos = col * 576 + kc * 64 + ((j ^ (col & 7)) << 3) + e;
    w_hi[pos] = h;
    w_mid[pos] = m;
    w_lo[pos] = lo;
}

// ---------------------------------------------------------------------------
// timeblock_mfma (r6, passing): 3-way-split bf16 MFMA GEMM. grid (64,3).
// ---------------------------------------------------------------------------
__global__ __launch_bounds__(512) void timeblock_mfma_kernel(
    const float* __restrict__ flow,
    const u16* __restrict__ w_hi, const u16* __restrict__ w_mid,
    const u16* __restrict__ w_lo,
    const float* __restrict__ b1, const float* __restrict__ b2,
    const float* __restrict__ b3, float* __restrict__ x1)
{
    __shared__ __align__(16) u16 As[3][128 * 64];
    __shared__ __align__(16) u16 Bs[3][192 * 64];

    const int tid = threadIdx.x;
    const int wv = tid >> 6, l = tid & 63;
    const int ln15 = l & 15, ln16 = l >> 4;
    const int wr = wv >> 1, wc = wv & 1;
    const int nodebase = blockIdx.x * 128;
    const int t = blockIdx.y;

    f4 acc[2][6];
#pragma unroll
    for (int rq = 0; rq < 2; ++rq)
#pragma unroll
        for (int nt = 0; nt < 6; ++nt) {
            acc[rq][nt][0] = 0.f; acc[rq][nt][1] = 0.f;
            acc[rq][nt][2] = 0.f; acc[rq][nt][3] = 0.f;
        }

    for (int kc = 0; kc < 9; ++kc) {
        __syncthreads();

#pragma unroll
        for (int u = tid; u < 1024; u += 512) {
            int r = u >> 3, j = u & 7;
            const float* srcp = flow + (size_t)(nodebase + r) * 960 + t * 192 + kc * 64 + j * 8;
            float4 f0 = *(const float4*)srcp;
            float4 f1 = *(const float4*)(srcp + 4);
            float fv[8] = { f0.x, f0.y, f0.z, f0.w, f1.x, f1.y, f1.z, f1.w };
            union { uint4 q; u16 a[8]; } uh, um, ul;
#pragma unroll
            for (int e = 0; e < 8; ++e) {
                u16 h = f2bf(fv[e]);   float r1 = fv[e] - bf2f(h);
                u16 m = f2bf(r1);      float r2 = r1 - bf2f(m);
                uh.a[e] = h; um.a[e] = m; ul.a[e] = f2bf(r2);
            }
            int pos = r * 64 + ((j ^ (r & 7)) << 3);
            *(uint4*)&As[0][pos] = uh.q;
            *(uint4*)&As[1][pos] = um.q;
            *(uint4*)&As[2][pos] = ul.q;
        }

#pragma unroll
        for (int arr = 0; arr < 3; ++arr) {
            const u16* wsrc = (arr == 0) ? w_hi : (arr == 1 ? w_mid : w_lo);
#pragma unroll
            for (int i = 0; i < 3; ++i) {
                int colg = wv * 24 + i * 8;
                const u16* srcp = wsrc + (size_t)(colg + (l >> 3)) * 576 + kc * 64 + (l & 7) * 8;
                u16* dstp = &Bs[arr][colg * 64];
                __builtin_amdgcn_global_load_lds(
                    (const __attribute__((address_space(1))) u32*)srcp,
                    (__attribute__((address_space(3))) u32*)dstp, 16, 0, 0);
            }
        }

        __syncthreads();

        bfrag af[2][3][2];
#pragma unroll
        for (int rq = 0; rq < 2; ++rq) {
            int arow = wr * 32 + rq * 16 + ln15;
#pragma unroll
            for (int ks = 0; ks < 2; ++ks) {
                int idx = arow * 64 + (((ks * 4 + ln16) ^ (arow & 7)) << 3);
                af[rq][0][ks] = *(const bfrag*)&As[0][idx];
                af[rq][1][ks] = *(const bfrag*)&As[1][idx];
                af[rq][2][ks] = *(const bfrag*)&As[2][idx];
            }
        }

#pragma unroll
        for (int cv = 0; cv < 3; ++cv) {
#pragma unroll
            for (int ntj = 0; ntj < 2; ++ntj) {
                int col = cv * 64 + wc * 32 + ntj * 16 + ln15;
                int nt = cv * 2 + ntj;
#pragma unroll
                for (int ks = 0; ks < 2; ++ks) {
                    int idx = col * 64 + (((ks * 4 + ln16) ^ (col & 7)) << 3);
                    bfrag bh = *(const bfrag*)&Bs[0][idx];
                    bfrag bm = *(const bfrag*)&Bs[1][idx];
                    bfrag bl = *(const bfrag*)&Bs[2][idx];
#pragma unroll
                    for (int rq = 0; rq < 2; ++rq) {
                        f4 a = acc[rq][nt];
                        a = __builtin_amdgcn_mfma_f32_16x16x32_bf16(af[rq][0][ks], bh, a, 0, 0, 0);
                        a = __builtin_amdgcn_mfma_f32_16x16x32_bf16(af[rq][0][ks], bm, a, 0, 0, 0);
                        a = __builtin_amdgcn_mfma_f32_16x16x32_bf16(af[rq][1][ks], bh, a, 0, 0, 0);
                        a = __builtin_amdgcn_mfma_f32_16x16x32_bf16(af[rq][0][ks], bl, a, 0, 0, 0);
                        a = __builtin_amdgcn_mfma_f32_16x16x32_bf16(af[rq][2][ks], bh, a, 0, 0, 0);
                        a = __builtin_amdgcn_mfma_f32_16x16x32_bf16(af[rq][1][ks], bm, a, 0, 0, 0);
                        acc[rq][nt] = a;
                    }
                }
            }
        }
    }

#pragma unroll
    for (int rq = 0; rq < 2; ++rq) {
#pragma unroll
        for (int ntj = 0; ntj < 2; ++ntj) {
            int o = wc * 32 + ntj * 16 + ln15;
            float bb1 = b1[o], bb2 = b2[o], bb3 = b3[o];
#pragma unroll
            for (int rg = 0; rg < 4; ++rg) {
                int node = nodebase + wr * 32 + rq * 16 + ln16 * 4 + rg;
                float c1 = acc[rq][0 * 2 + ntj][rg] + bb1;
                float c2 = acc[rq][1 * 2 + ntj][rg] + bb2;
                float c3 = acc[rq][2 * 2 + ntj][rg] + bb3;
                float sg = 1.0f / (1.0f + __expf(-c2));
                float v = c1 + sg + c3;
                x1[(size_t)node * 192 + t * 64 + o] = v > 0.f ? v : 0.f;
            }
        }
    }
}

// ---------------------------------------------------------------------------
// linear64_split (r4, passing)
// ---------------------------------------------------------------------------
__global__ __launch_bounds__(256) void linear64_split_kernel(
    const float* __restrict__ in, const float* __restrict__ W,
    u16* __restrict__ h_hi, u16* __restrict__ h_lo,
    u16* __restrict__ hTb_hi, u16* __restrict__ hTb_lo,
    int C, int H)
{
    __shared__ float xs[64][68];
    __shared__ float wsm[64][68];
    const int tid = threadIdx.x;
    const int g = blockIdx.y;
    const int rowbase = blockIdx.x * 64;
    const int rgrp = tid >> 4, cgrp = tid & 15;

    float acc[4][4] = {};
    for (int c0 = 0; c0 < C; c0 += 64) {
        __syncthreads();
        for (int i = tid; i < 4096; i += 256) {
            int r = i >> 6, cc = i & 63;
            xs[r][cc]  = in[(size_t)(rowbase + r) * C + c0 + cc];
            wsm[r][cc] = W[(size_t)(g * 64 + r) * C + c0 + cc];
        }
        __syncthreads();
        for (int cc = 0; cc < 64; cc += 4) {
            float4 xv[4], wv[4];
#pragma unroll
            for (int i = 0; i < 4; ++i)
                xv[i] = *reinterpret_cast<const float4*>(&xs[4 * rgrp + i][cc]);
#pragma unroll
            for (int j = 0; j < 4; ++j)
                wv[j] = *reinterpret_cast<const float4*>(&wsm[4 * cgrp + j][cc]);
#pragma unroll
            for (int i = 0; i < 4; ++i) {
#pragma unroll
                for (int j = 0; j < 4; ++j) {
                    acc[i][j] += xv[i].x * wv[j].x + xv[i].y * wv[j].y
                               + xv[i].z * wv[j].z + xv[i].w * wv[j].w;
                }
            }
        }
    }

    u16 hi[4][4], lo[4][4];
#pragma unroll
    for (int i = 0; i < 4; ++i)
#pragma unroll
        for (int j = 0; j < 4; ++j) {
            float a = acc[i][j];
            u16 h = f2bf(a);
            hi[i][j] = h;
            lo[i][j] = f2bf(a - bf2f(h));
        }

    const int b = rowbase >> 12;
    const size_t mapb = (size_t)(b * H + g) * (4096 * 64);

#pragma unroll
    for (int i = 0; i < 4; ++i) {
        int n = (rowbase & 4095) + 4 * rgrp + i;
        ushort4 vh = { hi[i][0], hi[i][1], hi[i][2], hi[i][3] };
        ushort4 vl = { lo[i][0], lo[i][1], lo[i][2], lo[i][3] };
        *(ushort4*)&h_hi[mapb + (size_t)n * 64 + 4 * cgrp] = vh;
        *(ushort4*)&h_lo[mapb + (size_t)n * 64 + 4 * cgrp] = vl;
    }
    {
        int n0 = (rowbase & 4095) + 4 * rgrp;
        size_t tb = mapb + ((size_t)(n0 >> 6) * 64) * 64;
#pragma unroll
        for (int j = 0; j < 4; ++j) {
            int d = 4 * cgrp + j;
            ushort4 vh = { hi[0][j], hi[1][j], hi[2][j], hi[3][j] };
            ushort4 vl = { lo[0][j], lo[1][j], lo[2][j], lo[3][j] };
            *(ushort4*)&hTb_hi[tb + (size_t)d * 64 + (n0 & 63)] = vh;
            *(ushort4*)&hTb_lo[tb + (size_t)d * 64 + (n0 & 63)] = vl;
        }
    }
}

// ---------------------------------------------------------------------------
// flash_mfma (r9): swapped S^T; P->PV handoff via in-wave shuffle transpose
// (no Ps LDS, no lgkm round-trip); optional column-chunk partial mode.
// mode 0: out = leaky(O/l + bias). mode 1: dump unnormalized O + (m,l).
// ---------------------------------------------------------------------------
__global__ __launch_bounds__(256) void flash_mfma_kernel(
    const u16* __restrict__ h_hi, const u16* __restrict__ h_lo,
    const u16* __restrict__ hTb_hi, const u16* __restrict__ hTb_lo,
    const float* __restrict__ graph, const float* __restrict__ bias,
    float* __restrict__ out, int H, int rstride,
    int ntiles, int mode, float* __restrict__ pO, float* __restrict__ pml)
{
    __shared__ __align__(16) u16 hcs[2][4][4096];   // [dbuf][K_hi,K_lo,V_hi,V_lo] 64 KB

    const int tid = threadIdx.x;
    const int wv = tid >> 6;
    const int l = tid & 63;
    const int ln15 = l & 15, ln16 = l >> 4;
    const int by = blockIdx.y;
    const int chunk = blockIdx.z;
    const int t0 = chunk * ntiles;
    const int bb = by / H, head = by % H;
    const size_t mapb = (size_t)by * (4096 * 64);
    const int rowbase = blockIdx.x * 64;

    // Q fragments (B-operand of swapped S^T): lane ln15 = q-row
    const int arow = rowbase + wv * 16 + ln15;
    bfrag ahi[2], alo[2];
#pragma unroll
    for (int ks = 0; ks < 2; ++ks) {
        ahi[ks] = *(const bfrag*)(h_hi + mapb + (size_t)arow * 64 + ks * 32 + ln16 * 8);
        alo[ks] = *(const bfrag*)(h_lo + mapb + (size_t)arow * 64 + ks * 32 + ln16 * 8);
    }

    const u16* gA = (wv == 0 ? h_hi : wv == 1 ? h_lo : wv == 2 ? hTb_hi : hTb_lo) + mapb;
    const int lrow = l >> 3;
    const int stoff = lrow * 64 + (((l & 7) ^ lrow) << 3);

#define STAGE(T, BUF)                                                          \
    {                                                                          \
        const u16* srcp = gA + (size_t)(T) * 4096 + stoff;                     \
        u16* dstp = &hcs[BUF][wv][0];                                          \
        _Pragma("unroll")                                                      \
        for (int i_ = 0; i_ < 8; ++i_)                                         \
            __builtin_amdgcn_global_load_lds(                                  \
                (const __attribute__((address_space(1))) u32*)(srcp + i_ * 512), \
                (__attribute__((address_space(3))) u32*)(dstp + i_ * 512),     \
                16, 0, 0);                                                     \
    }

    const float* grow = graph + (size_t)(rowbase + wv * 16 + ln15) * 4096 + ln16 * 4;

    float m_ = -3.0e38f, l_ = 0.f;
    f4 acco[4];
#pragma unroll
    for (int i = 0; i < 4; ++i) {
        acco[i][0] = 0.f; acco[i][1] = 0.f; acco[i][2] = 0.f; acco[i][3] = 0.f;
    }

    STAGE(t0, 0);
    float4 grC[4], grN[4];
#pragma unroll
    for (int cb = 0; cb < 4; ++cb)
        grC[cb] = *(const float4*)(grow + (size_t)t0 * 64 + cb * 16);

    // shuffle-transpose source lanes (see round-9 derivation)
    const int srcA = ln15 + ((((ln16 << 1)) & 3) << 4);
    const int srcB = ln15 + ((((ln16 << 1) + 1) & 3) << 4);
    const bool hi2 = (ln16 & 2) != 0;

    for (int tt = 0; tt < ntiles; ++tt) {
        const int t = t0 + tt;
        const int cur = tt & 1;

        __syncthreads();

        if (tt + 1 < ntiles) {
            STAGE(t + 1, cur ^ 1);
#pragma unroll
            for (int cb = 0; cb < 4; ++cb)
                grN[cb] = *(const float4*)(grow + (size_t)(t + 1) * 64 + cb * 16);
        }

        // ---- S^T phase: 24 MFMAs (swapped args) ----
        __builtin_amdgcn_s_setprio(1);
        f4 accs[4];
#pragma unroll
        for (int cb = 0; cb < 4; ++cb) {
            f4 a; a[0] = 0.f; a[1] = 0.f; a[2] = 0.f; a[3] = 0.f;
#pragma unroll
            for (int ks = 0; ks < 2; ++ks) {
                int c = cb * 16 + ln15;
                int idx = c * 64 + (((ks * 4 + ln16) * 8) ^ ((c & 7) << 3));
                bfrag bhi = *(const bfrag*)&hcs[cur][0][idx];
                bfrag blo = *(const bfrag*)&hcs[cur][1][idx];
                a = __builtin_amdgcn_mfma_f32_16x16x32_bf16(bhi, ahi[ks], a, 0, 0, 0);
                a = __builtin_amdgcn_mfma_f32_16x16x32_bf16(bhi, alo[ks], a, 0, 0, 0);
                a = __builtin_amdgcn_mfma_f32_16x16x32_bf16(blo, ahi[ks], a, 0, 0, 0);
            }
            accs[cb] = a;
        }
        __builtin_amdgcn_s_setprio(0);

        // ---- mask (thread-local row) ----
        float p[4][4];
#pragma unroll
        for (int cb = 0; cb < 4; ++cb) {
            float g0 = grC[cb].x, g1 = grC[cb].y, g2 = grC[cb].z, g3 = grC[cb].w;
            float v0 = accs[cb][0] * g0; p[cb][0] = (v0 == 0.f) ? -1e16f : v0;
            float v1 = accs[cb][1] * g1; p[cb][1] = (v1 == 0.f) ? -1e16f : v1;
            float v2 = accs[cb][2] * g2; p[cb][2] = (v2 == 0.f) ? -1e16f : v2;
            float v3 = accs[cb][3] * g3; p[cb][3] = (v3 == 0.f) ? -1e16f : v3;
        }

        // ---- row max: 15 in-thread + 2 shfl ----
        float tm = fmaxf(fmaxf(p[0][0], p[0][1]), fmaxf(p[0][2], p[0][3]));
#pragma unroll
        for (int cb = 1; cb < 4; ++cb)
            tm = fmaxf(tm, fmaxf(fmaxf(p[cb][0], p[cb][1]), fmaxf(p[cb][2], p[cb][3])));
        tm = fmaxf(tm, __shfl_xor(tm, 16));
        tm = fmaxf(tm, __shfl_xor(tm, 32));

        float mn = fmaxf(m_, tm);
        float corr = __expf(m_ - mn);

        // ---- exp + row sum ----
        float rs = 0.f;
#pragma unroll
        for (int cb = 0; cb < 4; ++cb) {
            p[cb][0] = __expf(p[cb][0] - mn);
            p[cb][1] = __expf(p[cb][1] - mn);
            p[cb][2] = __expf(p[cb][2] - mn);
            p[cb][3] = __expf(p[cb][3] - mn);
            rs += (p[cb][0] + p[cb][1]) + (p[cb][2] + p[cb][3]);
        }
        rs += __shfl_xor(rs, 16);
        rs += __shfl_xor(rs, 32);
        l_ = l_ * corr + rs;
        m_ = mn;

        // ---- rescale O ----
        float corr4[4];
#pragma unroll
        for (int rg = 0; rg < 4; ++rg)
            corr4[rg] = __shfl(corr, ln16 * 4 + rg);
#pragma unroll
        for (int nb = 0; nb < 4; ++nb) {
            acco[nb][0] *= corr4[0]; acco[nb][1] *= corr4[1];
            acco[nb][2] *= corr4[2]; acco[nb][3] *= corr4[3];
        }

        // ---- pack P hi/lo (cvt_pk); Uh/Ul[cb][b] = row u32 pos 8cb+2s+b ----
        u32 Uh[4][2], Ul[4][2];
#pragma unroll
        for (int cb = 0; cb < 4; ++cb) {
            u32 uh0 = cvtpk(p[cb][0], p[cb][1]);
            u32 uh1 = cvtpk(p[cb][2], p[cb][3]);
            float h0 = u2f(uh0 << 16), h1 = u2f(uh0 & 0xffff0000u);
            float h2 = u2f(uh1 << 16), h3 = u2f(uh1 & 0xffff0000u);
            Uh[cb][0] = uh0; Uh[cb][1] = uh1;
            Ul[cb][0] = cvtpk(p[cb][0] - h0, p[cb][1] - h1);
            Ul[cb][1] = cvtpk(p[cb][2] - h2, p[cb][3] - h3);
        }

        // ---- shuffle-transpose to PV A-frag layout ----
        bfrag pfh[2], pfl[2];
#pragma unroll
        for (int ks = 0; ks < 2; ++ks) {
            u32 w0a = (u32)__shfl((int)Uh[2 * ks + 0][0], srcA);
            u32 w0b = (u32)__shfl((int)Uh[2 * ks + 1][0], srcA);
            u32 w1a = (u32)__shfl((int)Uh[2 * ks + 0][1], srcA);
            u32 w1b = (u32)__shfl((int)Uh[2 * ks + 1][1], srcA);
            u32 w2a = (u32)__shfl((int)Uh[2 * ks + 0][0], srcB);
            u32 w2b = (u32)__shfl((int)Uh[2 * ks + 1][0], srcB);
            u32 w3a = (u32)__shfl((int)Uh[2 * ks + 0][1], srcB);
            u32 w3b = (u32)__shfl((int)Uh[2 * ks + 1][1], srcB);
            union { uint4 q; bfrag f; } ch;
            ch.q.x = hi2 ? w0b : w0a; ch.q.y = hi2 ? w1b : w1a;
            ch.q.z = hi2 ? w2b : w2a; ch.q.w = hi2 ? w3b : w3a;
            pfh[ks] = ch.f;

            u32 v0a = (u32)__shfl((int)Ul[2 * ks + 0][0], srcA);
            u32 v0b = (u32)__shfl((int)Ul[2 * ks + 1][0], srcA);
            u32 v1a = (u32)__shfl((int)Ul[2 * ks + 0][1], srcA);
            u32 v1b = (u32)__shfl((int)Ul[2 * ks + 1][1], srcA);
            u32 v2a = (u32)__shfl((int)Ul[2 * ks + 0][0], srcB);
            u32 v2b = (u32)__shfl((int)Ul[2 * ks + 1][0], srcB);
            u32 v3a = (u32)__shfl((int)Ul[2 * ks + 0][1], srcB);
            u32 v3b = (u32)__shfl((int)Ul[2 * ks + 1][1], srcB);
            union { uint4 q; bfrag f; } cl;
            cl.q.x = hi2 ? v0b : v0a; cl.q.y = hi2 ? v1b : v1a;
            cl.q.z = hi2 ? v2b : v2a; cl.q.w = hi2 ? v3b : v3a;
            pfl[ks] = cl.f;
        }

        // ---- PV phase: 24 MFMAs ----
        __builtin_amdgcn_s_setprio(1);
#pragma unroll
        for (int nb = 0; nb < 4; ++nb) {
#pragma unroll
            for (int ks = 0; ks < 2; ++ks) {
                int nr = nb * 16 + ln15;
                int idx = nr * 64 + (((ks * 4 + ln16) * 8) ^ ((nr & 7) << 3));
                bfrag vhi = *(const bfrag*)&hcs[cur][2][idx];
                bfrag vlo = *(const bfrag*)&hcs[cur][3][idx];
                acco[nb] = __builtin_amdgcn_mfma_f32_16x16x32_bf16(pfh[ks], vhi, acco[nb], 0, 0, 0);
                acco[nb] = __builtin_amdgcn_mfma_f32_16x16x32_bf16(pfh[ks], vlo, acco[nb], 0, 0, 0);
                acco[nb] = __builtin_amdgcn_mfma_f32_16x16x32_bf16(pfl[ks], vhi, acco[nb], 0, 0, 0);
            }
        }
        __builtin_amdgcn_s_setprio(0);

        if (tt + 1 < ntiles) {
#pragma unroll
            for (int cb = 0; cb < 4; ++cb)
                grC[cb] = grN[cb];
        }
    }
#undef STAGE

    if (mode == 0) {
        float l4[4];
#pragma unroll
        for (int rg = 0; rg < 4; ++rg)
            l4[rg] = __shfl(l_, ln16 * 4 + rg);

        const float* bv = bias + head * 64;
#pragma unroll
        for (int rg = 0; rg < 4; ++rg) {
            int row = rowbase + wv * 16 + ln16 * 4 + rg;
            float inv = 1.0f / l4[rg];
#pragma unroll
            for (int nb = 0; nb < 4; ++nb) {
                float v = acco[nb][rg] * inv + bv[nb * 16 + ln15];
                v = v > 0.f ? v : 0.01f * v;
                out[(size_t)(bb * N_NODES + row) * rstride + head * 64 + nb * 16 + ln15] = v;
            }
        }
    } else {
        // partial dump: unnormalized O + (m,l) per row
        int row = rowbase + wv * 16 + ln15;
        if (ln16 == 0) {
            size_t mi = (((size_t)by * 4 + chunk) * 4096 + row) * 2;
            pml[mi] = m_;
            pml[mi + 1] = l_;
        }
#pragma unroll
        for (int rg = 0; rg < 4; ++rg) {
            int row2 = rowbase + wv * 16 + ln16 * 4 + rg;
            size_t ob = (((size_t)by * 4 + chunk) * 4096 + row2) * 64;
#pragma unroll
            for (int nb = 0; nb < 4; ++nb)
                pO[ob + nb * 16 + ln15] = acco[nb][rg];
        }
    }
}

// ---------------------------------------------------------------------------
// merge: combine 4 column-chunk partials -> out = leaky(num/den + bias)
// ---------------------------------------------------------------------------
__global__ __launch_bounds__(256) void merge_kernel(
    const float* __restrict__ pO, const float* __restrict__ pml,
    const float* __restrict__ bias, float* __restrict__ out)
{
    int idx = blockIdx.x * 256 + threadIdx.x;   // 2*4096*64 total
    int feat = idx & 63;
    int row = (idx >> 6) & 4095;
    int map = idx >> 18;

    float mv[4], lv[4];
    float M = -3.0e38f;
#pragma unroll
    for (int c = 0; c < 4; ++c) {
        size_t mi = (((size_t)map * 4 + c) * 4096 + row) * 2;
        mv[c] = pml[mi];
        lv[c] = pml[mi + 1];
        M = fmaxf(M, mv[c]);
    }
    float den = 0.f, num = 0.f;
#pragma unroll
    for (int c = 0; c < 4; ++c) {
        float e = __expf(mv[c] - M);
        den += e * lv[c];
        num += e * pO[(((size_t)map * 4 + c) * 4096 + row) * 64 + feat];
    }
    float v = num / den + bias[feat];
    v = v > 0.f ? v : 0.01f * v;
    out[((size_t)map * 4096 + row) * 64 + feat] = v;
}

// ---------------------------------------------------------------------------
extern "C" void kernel_launch(void* const* d_in, const int* in_sizes, int n_in,
                              void* d_out, int out_size, void* d_ws, size_t ws_size,
                              hipStream_t stream)
{
    const float* flow = (const float*)d_in[0];
    const float* graph = (const float*)d_in[1];
    const float* w1 = (const float*)d_in[2];
    const float* b1 = (const float*)d_in[3];
    const float* w2 = (const float*)d_in[4];
    const float* b2 = (const float*)d_in[5];
    const float* w3 = (const float*)d_in[6];
    const float* b3 = (const float*)d_in[7];
    const float* Wh = (const float*)d_in[8];
    const float* bh = (const float*)d_in[9];
    const float* Wo = (const float*)d_in[10];
    const float* bo = (const float*)d_in[11];

    char* ws = (char*)d_ws;
    u16* wc_hi  = (u16*)ws;                          // aliases h1 region
    u16* wc_mid = wc_hi + (size_t)192 * 576;
    u16* wc_lo  = wc_mid + (size_t)192 * 576;

    u16* h1_hi  = (u16*)ws;
    u16* h1_lo  = h1_hi + (size_t)8 * 4096 * 64;
    u16* h1T_hi = h1_lo + (size_t)8 * 4096 * 64;
    u16* h1T_lo = h1T_hi + (size_t)8 * 4096 * 64;
    u16* h2_hi  = (u16*)ws;                          // reuse h1 region (4.19 MB)
    u16* h2_lo  = h2_hi + (size_t)2 * 4096 * 64;
    u16* h2T_hi = h2_lo + (size_t)2 * 4096 * 64;
    u16* h2T_lo = h2T_hi + (size_t)2 * 4096 * 64;
    float* pml  = (float*)(ws + (size_t)6 * 1024 * 1024);  // dead upper h-region
    float* xreg = (float*)(ws + (size_t)4 * 8 * 4096 * 64 * 2);
    float* x1 = xreg;
    float* x2 = xreg;
    float* pO = xreg;                                 // x2 dead by flash1 time
    float* outp = (float*)d_out;

    hipLaunchKernelGGL(wprep_kernel, dim3(432), dim3(256), 0, stream,
                       w1, w2, w3, wc_hi, wc_mid, wc_lo);
    hipLaunchKernelGGL(timeblock_mfma_kernel, dim3(64, 3), dim3(512), 0, stream,
                       flow, wc_hi, wc_mid, wc_lo, b1, b2, b3, x1);
    hipLaunchKernelGGL(linear64_split_kernel, dim3(128, 4), dim3(256), 0, stream,
                       x1, Wh, h1_hi, h1_lo, h1T_hi, h1T_lo, 192, 4);
    hipLaunchKernelGGL(flash_mfma_kernel, dim3(64, 8, 1), dim3(256), 0, stream,
                       h1_hi, h1_lo, h1T_hi, h1T_lo, graph, bh, x2, 4, 256,
                       64, 0, (float*)nullptr, (float*)nullptr);
    hipLaunchKernelGGL(linear64_split_kernel, dim3(128, 1), dim3(256), 0, stream,
                       x2, Wo, h2_hi, h2_lo, h2T_hi, h2T_lo, 256, 1);
    hipLaunchKernelGGL(flash_mfma_kernel, dim3(64, 2, 4), dim3(256), 0, stream,
                       h2_hi, h2_lo, h2T_hi, h2T_lo, graph, bo, (float*)nullptr, 1, 64,
                       16, 1, pO, pml);
    hipLaunchKernelGGL(merge_kernel, dim3(2048), dim3(256), 0, stream,
                       pO, pml, bo, outp);
}